// Round 7
// baseline (1355.859 us; speedup 1.0000x reference)
//
#include <hip/hip_runtime.h>

static const int kN = 50000;   // nodes
static const int kE = 300000;  // edges
static const int kG = 2048;    // graphs
static const int kT = 19;      // targets
static const int kSeg = kN * 4;  // CSR segments: key = dst*4 + rel
static const int kScanB = (kSeg + 256) / 256;  // 784 blocks covers kSeg+1

typedef __bf16 bf16;
typedef __bf16 bf16x8 __attribute__((ext_vector_type(8)));
typedef __bf16 bf16x4 __attribute__((ext_vector_type(4)));
typedef float  f32x4  __attribute__((ext_vector_type(4)));

// ---------------------------------------------------------------------------
// Stats pass layers 2/3: gather (CSR, +self) into LDS, GEMM1 vs w1t[r],
// accumulate per-channel sum/sumsq ONLY (h is NOT materialized -> saves the
// 102 MB h1 HBM round-trip that R0-R5 showed is the layer's cost).
// Grid (ceil(N/64), 4=rel), 512 threads (8 waves).
// ---------------------------------------------------------------------------
__global__ __launch_bounds__(512) void k_rstats(
    const bf16* __restrict__ Pb, const int* __restrict__ srcidx,
    const int* __restrict__ row_ptr, const bf16* __restrict__ w1t,
    float* __restrict__ stats)
{
    __shared__ bf16 As[64][264];
    const int t = threadIdx.x;
    const int r = blockIdx.y;
    const int m0 = blockIdx.x * 64;
    const int wave = t >> 6, lane = t & 63;
    const int l15 = lane & 15, lq = lane >> 4, koff = lq * 8;
    const int wn = wave * 32;

    const bf16* Bt = w1t + (long)r * 65536;
    const bf16* Bp[2];
#pragma unroll
    for (int j = 0; j < 2; ++j)
        Bp[j] = Bt + (long)(wn + j * 16 + l15) * 256 + koff;
    bf16x8 b0[2], b1[2];
#pragma unroll
    for (int j = 0; j < 2; ++j) b0[j] = *(const bf16x8*)(Bp[j]);

    // ---- gather phase: 8 rows per wave ----
    {
        const int rbase = m0 + wave * 8;
        int i0s[8], i1s[8];
#pragma unroll
        for (int rr = 0; rr < 8; ++rr) {
            int dc = rbase + rr; if (dc >= kN) dc = kN - 1;
            int seg = dc * 4 + r;
            i0s[rr] = row_ptr[seg];
            i1s[rr] = row_ptr[seg + 1];
        }
#pragma unroll
        for (int rr = 0; rr < 8; ++rr) {
            int dc = rbase + rr; if (dc >= kN) dc = kN - 1;
            bf16x4 sv = ((const bf16x4*)(Pb + (long)dc * 256))[lane];
            f32x4 a = {(float)sv[0], (float)sv[1], (float)sv[2], (float)sv[3]};
            int i = i0s[rr], i1 = i1s[rr];
            for (; i + 1 < i1; i += 2) {
                int s0 = srcidx[i], s1 = srcidx[i + 1];
                bf16x4 v0 = ((const bf16x4*)(Pb + (long)s0 * 256))[lane];
                bf16x4 v1 = ((const bf16x4*)(Pb + (long)s1 * 256))[lane];
                a[0] += (float)v0[0] + (float)v1[0];
                a[1] += (float)v0[1] + (float)v1[1];
                a[2] += (float)v0[2] + (float)v1[2];
                a[3] += (float)v0[3] + (float)v1[3];
            }
            if (i < i1) {
                bf16x4 v0 = ((const bf16x4*)(Pb + (long)srcidx[i] * 256))[lane];
                a[0] += (float)v0[0]; a[1] += (float)v0[1];
                a[2] += (float)v0[2]; a[3] += (float)v0[3];
            }
            bf16x4 o = {(bf16)a[0], (bf16)a[1], (bf16)a[2], (bf16)a[3]};
            *(bf16x4*)&As[wave * 8 + rr][lane * 4] = o;
        }
    }
    __syncthreads();

    // ---- GEMM1 vs w1t[r] ----
    const bf16* Ar[4];
#pragma unroll
    for (int i = 0; i < 4; ++i) Ar[i] = &As[i * 16 + l15][koff];

    f32x4 acc[4][2];
#pragma unroll
    for (int i = 0; i < 4; ++i)
#pragma unroll
        for (int j = 0; j < 2; ++j) acc[i][j] = (f32x4){0.f, 0.f, 0.f, 0.f};

#pragma unroll
    for (int kt = 0; kt < 256; kt += 32) {
        int kn = kt + 32; if (kn >= 256) kn = 0;
#pragma unroll
        for (int j = 0; j < 2; ++j) b1[j] = *(const bf16x8*)(Bp[j] + kn);
        bf16x8 a[4];
#pragma unroll
        for (int i = 0; i < 4; ++i) a[i] = *(const bf16x8*)(Ar[i] + kt);
#pragma unroll
        for (int i = 0; i < 4; ++i)
#pragma unroll
            for (int j = 0; j < 2; ++j)
                acc[i][j] = __builtin_amdgcn_mfma_f32_16x16x32_bf16(a[i], b0[j], acc[i][j], 0, 0, 0);
#pragma unroll
        for (int j = 0; j < 2; ++j) b0[j] = b1[j];
    }

    // ---- stats only (bf16-rounded, matching fused recompute) ----
    const int cB = r * 256;
    float sv[2] = {0, 0}, qv[2] = {0, 0};
#pragma unroll
    for (int i = 0; i < 4; ++i) {
        int rowb = m0 + i * 16 + lq * 4;
#pragma unroll
        for (int rr = 0; rr < 4; ++rr) {
            int gm = rowb + rr;
            if (gm < kN) {
#pragma unroll
                for (int j = 0; j < 2; ++j) {
                    float f = (float)(bf16)acc[i][j][rr];
                    sv[j] += f; qv[j] += f * f;
                }
            }
        }
    }
#pragma unroll
    for (int j = 0; j < 2; ++j) {
        float s = sv[j], q = qv[j];
        s += __shfl_xor(s, 16); s += __shfl_xor(s, 32);
        q += __shfl_xor(q, 16); q += __shfl_xor(q, 32);
        if (lq == 0) {
            int gn = cB + wn + j * 16 + l15;
            atomicAdd(&stats[gn], s);
            atomicAdd(&stats[1024 + gn], q);
        }
    }
}

// ---------------------------------------------------------------------------
// Stats pass layer 1: h = a1b[r] @ w1tL1[r] (K=32), stats only.
// ---------------------------------------------------------------------------
__global__ __launch_bounds__(512) void k_l1stats(
    const bf16* __restrict__ a1b, const bf16* __restrict__ w1tL1,
    float* __restrict__ stats)
{
    const int t = threadIdx.x;
    const int r = blockIdx.y;
    const int m0 = blockIdx.x * 128;
    const int wave = t >> 6, lane = t & 63;
    const int l15 = lane & 15, lq = lane >> 4, koff = lq * 8;
    const int wm = (wave & 1) * 64, wn = (wave >> 1) * 64;

    bf16x8 a[4], b[4];
#pragma unroll
    for (int i = 0; i < 4; ++i) {
        int gm = m0 + wm + i * 16 + l15;
        if (gm >= kN) gm = kN - 1;
        a[i] = *(const bf16x8*)(a1b + ((long)r * kN + gm) * 32 + koff);
    }
#pragma unroll
    for (int j = 0; j < 4; ++j)
        b[j] = *(const bf16x8*)(w1tL1 + (long)r * 8192 + (long)(wn + j * 16 + l15) * 32 + koff);

    f32x4 acc[4][4];
#pragma unroll
    for (int i = 0; i < 4; ++i)
#pragma unroll
        for (int j = 0; j < 4; ++j)
            acc[i][j] = __builtin_amdgcn_mfma_f32_16x16x32_bf16(a[i], b[j],
                        (f32x4){0.f, 0.f, 0.f, 0.f}, 0, 0, 0);

    const int cB = r * 256;
    float sv[4] = {0,0,0,0}, qv[4] = {0,0,0,0};
#pragma unroll
    for (int i = 0; i < 4; ++i) {
        int rowb = m0 + wm + i * 16 + lq * 4;
#pragma unroll
        for (int rr = 0; rr < 4; ++rr) {
            int gm = rowb + rr;
            if (gm < kN) {
#pragma unroll
                for (int j = 0; j < 4; ++j) {
                    float f = (float)(bf16)acc[i][j][rr];
                    sv[j] += f; qv[j] += f * f;
                }
            }
        }
    }
#pragma unroll
    for (int j = 0; j < 4; ++j) {
        float s = sv[j], q = qv[j];
        s += __shfl_xor(s, 16); s += __shfl_xor(s, 32);
        q += __shfl_xor(q, 16); q += __shfl_xor(q, 32);
        if (lq == 0) {
            int gn = cB + wn + j * 16 + l15;
            atomicAdd(&stats[gn], s);
            atomicAdd(&stats[1024 + gn], q);
        }
    }
}

// ---------------------------------------------------------------------------
// FUSED layer: out = relu( Ain@sw + sum_r max(h_r+u,0) @ (scl*w2_r) + bias ),
// h_r recomputed in-tile (gather + GEMM1) and never written to global.
// Grid (ceil(N/64)), 512 thr (8 waves). Per wave: all 64 rows x 32-col slice.
// Phases per r (!L1): SYNC; gather X->As; SYNC; h=As@w1[r] (regs); SYNC;
//   Hs=max(h+u,0)->As; SYNC; out += As@w2'[r].   L1: h from a1b regs (K=32).
// LDS 33.8 KB (one 64x264 buffer, reused each phase).
// ---------------------------------------------------------------------------
template<bool L1, bool PoolOut>
__global__ __launch_bounds__(512) void k_fused(
    const bf16* __restrict__ Ain,   // L1: xb1 [N,128] row-major; else Pb [N,256]
    const bf16* __restrict__ a1b,   // L1 only
    const int* __restrict__ srcidx, const int* __restrict__ row_ptr,
    const bf16* __restrict__ w1B,   // L1: [4][256][32]; else [4][256][256] (n-major, k contig)
    const bf16* __restrict__ swB,   // L1: [256][128]; else [256][256] (n-major, k contig)
    const bf16* __restrict__ w2B,   // [4][256][256] n-major k-contig, scl-scaled
    bf16* __restrict__ Cout, int M,
    const float* __restrict__ bias, const float* __restrict__ uu,
    const int* __restrict__ batch, float* __restrict__ pooled)
{
    __shared__ bf16 As[64][264];
    const int t = threadIdx.x;
    const int m0 = blockIdx.x * 64;
    const int wave = t >> 6, lane = t & 63;
    const int l15 = lane & 15, lq = lane >> 4, koff = lq * 8;
    const int wn = wave * 32;
    constexpr int AW = L1 ? 128 : 256;   // Ain width = sw K

    // ---- stage Ain tile into As ----
    {
        const int row = t >> 3, cg = t & 7;
        int gm = m0 + row; if (gm >= M) gm = M - 1;
#pragma unroll
        for (int u2 = 0; u2 < (L1 ? 2 : 4); ++u2) {
            int col = cg * (L1 ? 16 : 32) + u2 * 8;
            *(bf16x8*)&As[row][col] = *(const bf16x8*)(Ain + (long)gm * AW + col);
        }
    }
    __syncthreads();

    f32x4 outacc[4][2];
#pragma unroll
    for (int i = 0; i < 4; ++i)
#pragma unroll
        for (int j = 0; j < 2; ++j) outacc[i][j] = (f32x4){0.f, 0.f, 0.f, 0.f};

    // ---- self-linear: out = As @ swB ----
    {
        const bf16* Bq0 = swB + (long)(wn + l15) * AW + koff;
        const bf16* Bq1 = swB + (long)(wn + 16 + l15) * AW + koff;
#pragma unroll
        for (int kt = 0; kt < AW; kt += 32) {
            bf16x8 a[4];
#pragma unroll
            for (int i = 0; i < 4; ++i) a[i] = *(const bf16x8*)&As[i * 16 + l15][kt + koff];
            bf16x8 b0 = *(const bf16x8*)(Bq0 + kt);
            bf16x8 b1 = *(const bf16x8*)(Bq1 + kt);
#pragma unroll
            for (int i = 0; i < 4; ++i) {
                outacc[i][0] = __builtin_amdgcn_mfma_f32_16x16x32_bf16(a[i], b0, outacc[i][0], 0, 0, 0);
                outacc[i][1] = __builtin_amdgcn_mfma_f32_16x16x32_bf16(a[i], b1, outacc[i][1], 0, 0, 0);
            }
        }
    }

    // ---- relation loop ----
#pragma unroll 1
    for (int r = 0; r < 4; ++r) {
        f32x4 hacc[4][2];
        if (L1) {
            bf16x8 a[4];
#pragma unroll
            for (int i = 0; i < 4; ++i) {
                int gm = m0 + i * 16 + l15; if (gm >= M) gm = M - 1;
                a[i] = *(const bf16x8*)(a1b + ((long)r * kN + gm) * 32 + koff);
            }
            bf16x8 b0 = *(const bf16x8*)(w1B + (long)r * 8192 + (long)(wn + l15) * 32 + koff);
            bf16x8 b1 = *(const bf16x8*)(w1B + (long)r * 8192 + (long)(wn + 16 + l15) * 32 + koff);
#pragma unroll
            for (int i = 0; i < 4; ++i) {
                hacc[i][0] = __builtin_amdgcn_mfma_f32_16x16x32_bf16(a[i], b0, (f32x4){0.f,0.f,0.f,0.f}, 0, 0, 0);
                hacc[i][1] = __builtin_amdgcn_mfma_f32_16x16x32_bf16(a[i], b1, (f32x4){0.f,0.f,0.f,0.f}, 0, 0, 0);
            }
            __syncthreads();   // readers of As (sw / prev phase C) done
        } else {
            __syncthreads();   // readers of As (sw / prev phase C) done
            // gather X = self + agg into As (8 rows/wave)
            {
                const int rbase = m0 + wave * 8;
                int i0s[8], i1s[8];
#pragma unroll
                for (int rr = 0; rr < 8; ++rr) {
                    int dc = rbase + rr; if (dc >= kN) dc = kN - 1;
                    int seg = dc * 4 + r;
                    i0s[rr] = row_ptr[seg];
                    i1s[rr] = row_ptr[seg + 1];
                }
#pragma unroll
                for (int rr = 0; rr < 8; ++rr) {
                    int dc = rbase + rr; if (dc >= kN) dc = kN - 1;
                    bf16x4 sv = ((const bf16x4*)(Ain + (long)dc * 256))[lane];
                    f32x4 ag = {(float)sv[0], (float)sv[1], (float)sv[2], (float)sv[3]};
                    int i = i0s[rr], i1 = i1s[rr];
                    for (; i + 1 < i1; i += 2) {
                        int s0 = srcidx[i], s1 = srcidx[i + 1];
                        bf16x4 v0 = ((const bf16x4*)(Ain + (long)s0 * 256))[lane];
                        bf16x4 v1 = ((const bf16x4*)(Ain + (long)s1 * 256))[lane];
                        ag[0] += (float)v0[0] + (float)v1[0];
                        ag[1] += (float)v0[1] + (float)v1[1];
                        ag[2] += (float)v0[2] + (float)v1[2];
                        ag[3] += (float)v0[3] + (float)v1[3];
                    }
                    if (i < i1) {
                        bf16x4 v0 = ((const bf16x4*)(Ain + (long)srcidx[i] * 256))[lane];
                        ag[0] += (float)v0[0]; ag[1] += (float)v0[1];
                        ag[2] += (float)v0[2]; ag[3] += (float)v0[3];
                    }
                    bf16x4 o = {(bf16)ag[0], (bf16)ag[1], (bf16)ag[2], (bf16)ag[3]};
                    *(bf16x4*)&As[wave * 8 + rr][lane * 4] = o;
                }
            }
            __syncthreads();
            // h = As @ w1t[r]
#pragma unroll
            for (int i = 0; i < 4; ++i)
#pragma unroll
                for (int j = 0; j < 2; ++j) hacc[i][j] = (f32x4){0.f, 0.f, 0.f, 0.f};
            {
                const bf16* Bq0 = w1B + (long)r * 65536 + (long)(wn + l15) * 256 + koff;
                const bf16* Bq1 = w1B + (long)r * 65536 + (long)(wn + 16 + l15) * 256 + koff;
#pragma unroll
                for (int kt = 0; kt < 256; kt += 32) {
                    bf16x8 a[4];
#pragma unroll
                    for (int i = 0; i < 4; ++i) a[i] = *(const bf16x8*)&As[i * 16 + l15][kt + koff];
                    bf16x8 b0 = *(const bf16x8*)(Bq0 + kt);
                    bf16x8 b1 = *(const bf16x8*)(Bq1 + kt);
#pragma unroll
                    for (int i = 0; i < 4; ++i) {
                        hacc[i][0] = __builtin_amdgcn_mfma_f32_16x16x32_bf16(a[i], b0, hacc[i][0], 0, 0, 0);
                        hacc[i][1] = __builtin_amdgcn_mfma_f32_16x16x32_bf16(a[i], b1, hacc[i][1], 0, 0, 0);
                    }
                }
            }
            __syncthreads();   // done reading As before overwrite
        }

        // ---- Hs = max(bf16(h) + u, 0) -> As ----
        {
            const int cb = r * 256;
            float u0 = uu[cb + wn + l15];
            float u1 = uu[cb + wn + 16 + l15];
#pragma unroll
            for (int i = 0; i < 4; ++i) {
                int rowb = i * 16 + lq * 4;
#pragma unroll
                for (int rr = 0; rr < 4; ++rr) {
                    As[rowb + rr][wn + l15]      = (bf16)fmaxf((float)(bf16)hacc[i][0][rr] + u0, 0.f);
                    As[rowb + rr][wn + 16 + l15] = (bf16)fmaxf((float)(bf16)hacc[i][1][rr] + u1, 0.f);
                }
            }
        }
        __syncthreads();

        // ---- out += As(Hs) @ w2'[r] ----
        {
            const bf16* Bq0 = w2B + (long)r * 65536 + (long)(wn + l15) * 256 + koff;
            const bf16* Bq1 = w2B + (long)r * 65536 + (long)(wn + 16 + l15) * 256 + koff;
#pragma unroll
            for (int kt = 0; kt < 256; kt += 32) {
                bf16x8 a[4];
#pragma unroll
                for (int i = 0; i < 4; ++i) a[i] = *(const bf16x8*)&As[i * 16 + l15][kt + koff];
                bf16x8 b0 = *(const bf16x8*)(Bq0 + kt);
                bf16x8 b1 = *(const bf16x8*)(Bq1 + kt);
#pragma unroll
                for (int i = 0; i < 4; ++i) {
                    outacc[i][0] = __builtin_amdgcn_mfma_f32_16x16x32_bf16(a[i], b0, outacc[i][0], 0, 0, 0);
                    outacc[i][1] = __builtin_amdgcn_mfma_f32_16x16x32_bf16(a[i], b1, outacc[i][1], 0, 0, 0);
                }
            }
        }
    }

    // ---- epilogue: relu(out + bias) -> Cout / pooled ----
#pragma unroll
    for (int i = 0; i < 4; ++i) {
        int rowb = m0 + i * 16 + lq * 4;
#pragma unroll
        for (int rr = 0; rr < 4; ++rr) {
            int gm = rowb + rr;
            if (gm < M) {
                int g = PoolOut ? batch[gm] : 0;
#pragma unroll
                for (int j = 0; j < 2; ++j) {
                    int gn = wn + j * 16 + l15;
                    float v = fmaxf(outacc[i][j][rr] + bias[gn], 0.f);
                    if (PoolOut) atomicAdd(&pooled[(long)g * 256 + gn], v);
                    else         Cout[(long)gm * 256 + gn] = (bf16)v;
                }
            }
        }
    }
}

// ---------------------------------------------------------------------------
// CSR build
__global__ void k_hist(const int* __restrict__ ei, const int* __restrict__ et,
                       int* __restrict__ hist)
{
    int e = blockIdx.x * 256 + threadIdx.x;
    if (e >= kE) return;
    atomicAdd(&hist[ei[kE + e] * 4 + et[e]], 1);
}

__global__ void k_scan1(const int* __restrict__ hist, int* __restrict__ bsum)
{
    __shared__ int sd[256];
    int i = blockIdx.x * 256 + threadIdx.x;
    sd[threadIdx.x] = (i < kSeg) ? hist[i] : 0;
    __syncthreads();
    for (int o = 128; o > 0; o >>= 1) {
        if (threadIdx.x < o) sd[threadIdx.x] += sd[threadIdx.x + o];
        __syncthreads();
    }
    if (threadIdx.x == 0) bsum[blockIdx.x] = sd[0];
}

__global__ __launch_bounds__(1024) void k_scan2(const int* __restrict__ bsum,
                                                int* __restrict__ boff)
{
    __shared__ int sd[1024];
    int t = threadIdx.x;
    sd[t] = (t < kScanB) ? bsum[t] : 0;
    __syncthreads();
    for (int o = 1; o < 1024; o <<= 1) {
        int v = (t >= o) ? sd[t - o] : 0;
        __syncthreads();
        sd[t] += v;
        __syncthreads();
    }
    if (t < kScanB) boff[t] = (t == 0) ? 0 : sd[t - 1];
}

__global__ void k_scan3(const int* __restrict__ hist, const int* __restrict__ boff,
                        int* __restrict__ row_ptr, int* __restrict__ cursor)
{
    __shared__ int sd[256];
    int i = blockIdx.x * 256 + threadIdx.x;
    int v = (i < kSeg) ? hist[i] : 0;
    sd[threadIdx.x] = v;
    __syncthreads();
    for (int o = 1; o < 256; o <<= 1) {
        int u = (threadIdx.x >= o) ? sd[threadIdx.x - o] : 0;
        __syncthreads();
        sd[threadIdx.x] += u;
        __syncthreads();
    }
    if (i <= kSeg) {
        int excl = boff[blockIdx.x] + sd[threadIdx.x] - v;
        row_ptr[i] = excl;
        if (i < kSeg) cursor[i] = excl;
    }
}

__global__ void k_fill(const int* __restrict__ ei, const int* __restrict__ et,
                       int* __restrict__ cursor, int* __restrict__ srcidx)
{
    int e = blockIdx.x * 256 + threadIdx.x;
    if (e >= kE) return;
    int key = ei[kE + e] * 4 + et[e];
    int pos = atomicAdd(&cursor[key], 1);
    srcidx[pos] = ei[e];
}

// ---------------------------------------------------------------------------
// layer-1 aggregate: a1b[r][d][ch] = bf16( x[d][ch] + sum_src x[src][ch] ), ch<11
__global__ void k_agg11(const float* __restrict__ x, const int* __restrict__ srcidx,
                        const int* __restrict__ row_ptr, bf16* __restrict__ a1b)
{
    long gid = (long)blockIdx.x * 256 + threadIdx.x;
    if (gid >= (long)kSeg * 32) return;
    int ch  = (int)(gid & 31);
    int seg = (int)(gid >> 5);
    int d = seg >> 2, r = seg & 3;
    float acc = 0.f;
    if (ch < 11) {
        acc = x[(long)d * 11 + ch];
        int i0 = row_ptr[seg], i1 = row_ptr[seg + 1];
        for (int i = i0; i < i1; ++i) acc += x[(long)srcidx[i] * 11 + ch];
    }
    a1b[((long)r * kN + d) * 32 + ch] = (bf16)acc;
}

// x [N,11] fp32 -> xb1 [N,128] bf16 row-major zero-padded
__global__ void k_xpad(const float* __restrict__ x, bf16* __restrict__ xb1)
{
    long gid = (long)blockIdx.x * 256 + threadIdx.x;
    if (gid >= (long)kN * 128) return;
    int c = (int)(gid & 127); long d = gid >> 7;
    xb1[gid] = (c < 11) ? (bf16)x[d * 11 + c] : (bf16)0.f;
}

// weight transpose-pack: in [K,N] fp32 -> out[n*ldout + coff + k] bf16
__global__ void k_wt_s(const float* __restrict__ in, bf16* __restrict__ out,
                       int K, int N, int ldout, int coff)
{
    int i = blockIdx.x * 256 + threadIdx.x;
    if (i >= K * N) return;
    int n = i / K, k = i - n * K;
    out[(long)n * ldout + coff + k] = (bf16)in[(long)k * N + n];
}

// scaled w2 pack: out[r][n*256+k] = w2[r][k][n] * scl[r*256+k]
__global__ void k_w2p(const float* __restrict__ w2, const float* __restrict__ scl,
                      bf16* __restrict__ out)
{
    int i = blockIdx.x * 256 + threadIdx.x;   // < 4*65536
    if (i >= 4 * 65536) return;
    int r = i >> 16, rem = i & 65535, n = rem >> 8, k = rem & 255;
    out[i] = (bf16)(w2[(long)r * 65536 + (long)k * 256 + n] * scl[r * 256 + k]);
}

// layer-1 w1 pack: [4][11][256] fp32 -> [4][256][32] bf16 zero-padded
__global__ void k_wtL1(const float* __restrict__ w1, bf16* __restrict__ out)
{
    int i = blockIdx.x * 256 + threadIdx.x;
    if (i >= 4 * 256 * 32) return;
    int r = i >> 13, rem = i & 8191, n = rem >> 5, k = rem & 31;
    out[i] = (k < 11) ? (bf16)w1[(long)r * 11 * 256 + (long)k * 256 + n] : (bf16)0.f;
}

// BN params: scl = g*rsqrt(var+eps) (>0, g=ones); u = bt/scl - mu so that
// relu(h*scl+shf) = scl*max(h+u,0); scl folded into w2 by k_w2p.
__global__ void k_bn_params(const float* __restrict__ stats,
                            const float* __restrict__ g, const float* __restrict__ bt,
                            float* __restrict__ scl, float* __restrict__ uu)
{
    int c = blockIdx.x * 256 + threadIdx.x;  // < 1024
    const float invN = 1.0f / (float)kN;
    float mu  = stats[c] * invN;
    float var = stats[1024 + c] * invN - mu * mu;
    float sc  = g[c] * rsqrtf(var + 1e-5f);
    scl[c] = sc;
    uu[c]  = bt[c] / sc - mu;
}

__global__ void k_bias_total(const float* sb0, const float* b20,
                             const float* sb1, const float* b21,
                             const float* sb2, const float* b22,
                             float* __restrict__ btt)
{
    int l = blockIdx.x, j = threadIdx.x;
    const float* sb = (l == 0) ? sb0 : (l == 1) ? sb1 : sb2;
    const float* b2 = (l == 0) ? b20 : (l == 1) ? b21 : b22;
    float v = sb[j];
#pragma unroll
    for (int r = 0; r < 4; ++r) v += b2[r * 256 + j];
    btt[l * 256 + j] = v;
}

__global__ void k_counts(const int* __restrict__ batch, float* __restrict__ counts)
{
    int v = blockIdx.x * 256 + threadIdx.x;
    if (v < kN) atomicAdd(&counts[batch[v]], 1.0f);
}

__global__ __launch_bounds__(64) void k_head(const float* __restrict__ pooled,
                                             const float* __restrict__ counts,
                                             const float* __restrict__ lw,
                                             const float* __restrict__ lb,
                                             float* __restrict__ out)
{
    int g = blockIdx.x;
    int l = threadIdx.x;
    float inv = 1.0f / fmaxf(counts[g], 1.0f);
    float acc[kT];
#pragma unroll
    for (int t = 0; t < kT; ++t) acc[t] = 0.f;
    for (int k = l; k < 256; k += 64) {
        float p = pooled[((long)g << 8) + k] * inv;
#pragma unroll
        for (int t = 0; t < kT; ++t) acc[t] = fmaf(p, lw[k * kT + t], acc[t]);
    }
#pragma unroll
    for (int off = 32; off > 0; off >>= 1)
#pragma unroll
        for (int t = 0; t < kT; ++t) acc[t] += __shfl_down(acc[t], off);
    if (l == 0) {
#pragma unroll
        for (int t = 0; t < kT; ++t) out[(long)g * kT + t] = acc[t] + lb[t];
    }
}

// ---------------------------------------------------------------------------
extern "C" void kernel_launch(void* const* d_in, const int* in_sizes, int n_in,
                              void* d_out, int out_size, void* d_ws, size_t ws_size,
                              hipStream_t stream)
{
    const float* x     = (const float*)d_in[0];
    const int*   ei    = (const int*)d_in[1];
    const int*   et    = (const int*)d_in[2];
    const int*   batch = (const int*)d_in[3];

    const float *sw[3], *sb[3], *w1[3], *gmm[3], *btm[3], *w2[3], *b2[3];
    for (int l = 0; l < 3; ++l) {
        int b = 4 + l * 8;
        sw[l]  = (const float*)d_in[b + 0];
        sb[l]  = (const float*)d_in[b + 1];
        w1[l]  = (const float*)d_in[b + 2];
        // b+3 = b1 (cancels inside BatchNorm)
        gmm[l] = (const float*)d_in[b + 4];
        btm[l] = (const float*)d_in[b + 5];
        w2[l]  = (const float*)d_in[b + 6];
        b2[l]  = (const float*)d_in[b + 7];
    }
    const float* lin_w = (const float*)d_in[28];
    const float* lin_b = (const float*)d_in[29];
    float* out = (float*)d_out;
    (void)in_sizes; (void)n_in; (void)out_size;

    // ---- workspace (~90 MB; h1 eliminated) ----
    char* wsb = (char*)d_ws;
    size_t off = 0;
    auto alloc = [&](size_t bytes) { void* p = wsb + off; off = (off + bytes + 255) & ~(size_t)255; return p; };
    bf16*  Pb0    = (bf16*) alloc((size_t)kN * 256 * 2);
    bf16*  Pb1    = (bf16*) alloc((size_t)kN * 256 * 2);
    bf16*  a1b    = (bf16*) alloc((size_t)4 * kN * 32 * 2);
    bf16*  xb1    = (bf16*) alloc((size_t)kN * 128 * 2);
    bf16*  w1t    = (bf16*) alloc((size_t)2 * 4 * 65536 * 2);   // layers 2,3
    bf16*  w1tL1  = (bf16*) alloc((size_t)4 * 256 * 32 * 2);
    bf16*  Bsw1   = (bf16*) alloc((size_t)256 * 128 * 2);       // sw layer1 (K=128 pad)
    bf16*  Bsw2   = (bf16*) alloc((size_t)256 * 256 * 2);
    bf16*  Bsw3   = (bf16*) alloc((size_t)256 * 256 * 2);
    bf16*  W2p    = (bf16*) alloc((size_t)4 * 65536 * 2);       // scaled w2 (per-layer reuse)
    int*   hist   = (int*)  alloc((size_t)(kSeg + 1) * 4);
    int*   row_ptr= (int*)  alloc((size_t)(kSeg + 1) * 4);
    int*   cursor = (int*)  alloc((size_t)kSeg * 4);
    int*   srcidx = (int*)  alloc((size_t)kE * 4);
    int*   bsum   = (int*)  alloc((size_t)kScanB * 4);
    int*   boff   = (int*)  alloc((size_t)kScanB * 4);
    float* stats  = (float*)alloc(2048 * 4);
    float* scl    = (float*)alloc(1024 * 4);
    float* uu     = (float*)alloc(1024 * 4);
    float* btt    = (float*)alloc(3 * 256 * 4);
    float* pooled = (float*)alloc((size_t)kG * 256 * 4);
    float* counts = (float*)alloc(kG * 4);
    if (ws_size < off) return;  // clean absmax-fail instead of OOB crash

    const dim3 gL1((kN + 127) / 128, 4);  // l1 stats grid (512 thr)
    const dim3 gR((kN + 63) / 64, 4);     // rstats grid (512 thr)
    const dim3 gF((kN + 63) / 64);        // fused grid (512 thr, 64-row tile)

    // ---- CSR build (parallel scan) + weight prepack ----
    hipMemsetAsync(hist, 0, (size_t)(kSeg + 1) * 4, stream);
    k_hist<<<(kE + 255) / 256, 256, 0, stream>>>(ei, et, hist);
    k_scan1<<<kScanB, 256, 0, stream>>>(hist, bsum);
    k_scan2<<<1, 1024, 0, stream>>>(bsum, boff);
    k_scan3<<<kScanB, 256, 0, stream>>>(hist, boff, row_ptr, cursor);
    k_fill<<<(kE + 255) / 256, 256, 0, stream>>>(ei, et, cursor, srcidx);

    k_bias_total<<<3, 256, 0, stream>>>(sb[0], b2[0], sb[1], b2[1], sb[2], b2[2], btt);
    k_xpad<<<(int)(((long)kN * 128 + 255) / 256), 256, 0, stream>>>(x, xb1);
    k_wtL1<<<(4 * 256 * 32 + 255) / 256, 256, 0, stream>>>(w1[0], w1tL1);
    for (int l = 1; l < 3; ++l)
        for (int r = 0; r < 4; ++r)
            k_wt_s<<<256, 256, 0, stream>>>(w1[l] + (long)r * 65536,
                                            w1t + (long)(l - 1) * 4 * 65536 + (long)r * 65536,
                                            256, 256, 256, 0);
    hipMemsetAsync(Bsw1, 0, (size_t)256 * 128 * 2, stream);
    k_wt_s<<<(11 * 256 + 255) / 256, 256, 0, stream>>>(sw[0], Bsw1, 11, 256, 128, 0);
    k_wt_s<<<256, 256, 0, stream>>>(sw[1], Bsw2, 256, 256, 256, 0);
    k_wt_s<<<256, 256, 0, stream>>>(sw[2], Bsw3, 256, 256, 256, 0);

    k_counts<<<(kN + 255) / 256, 256, 0, stream>>>(batch, counts);  // counts poisoned -> must init
    hipMemsetAsync(pooled, 0, (size_t)kG * 256 * 4, stream);

    // ---------------- layer 1 ----------------
    k_agg11<<<(int)(((long)kSeg * 32 + 255) / 256), 256, 0, stream>>>(x, srcidx, row_ptr, a1b);
    hipMemsetAsync(stats, 0, 2048 * 4, stream);
    k_l1stats<<<gL1, 512, 0, stream>>>(a1b, w1tL1, stats);
    k_bn_params<<<4, 256, 0, stream>>>(stats, gmm[0], btm[0], scl, uu);
    k_w2p<<<1024, 256, 0, stream>>>(w2[0], scl, W2p);
    k_fused<true, false><<<gF, 512, 0, stream>>>(xb1, a1b, srcidx, row_ptr,
                                                 w1tL1, Bsw1, W2p,
                                                 Pb0, kN, btt + 0, uu, nullptr, nullptr);

    // ---------------- layer 2 ----------------
    hipMemsetAsync(stats, 0, 2048 * 4, stream);
    k_rstats<<<gR, 512, 0, stream>>>(Pb0, srcidx, row_ptr, w1t, stats);
    k_bn_params<<<4, 256, 0, stream>>>(stats, gmm[1], btm[1], scl, uu);
    k_w2p<<<1024, 256, 0, stream>>>(w2[1], scl, W2p);
    k_fused<false, false><<<gF, 512, 0, stream>>>(Pb0, nullptr, srcidx, row_ptr,
                                                  w1t, Bsw2, W2p,
                                                  Pb1, kN, btt + 256, uu, nullptr, nullptr);

    // ---------------- layer 3 (pool fused) ----------------
    hipMemsetAsync(stats, 0, 2048 * 4, stream);
    k_rstats<<<gR, 512, 0, stream>>>(Pb1, srcidx, row_ptr, w1t + (size_t)4 * 65536, stats);
    k_bn_params<<<4, 256, 0, stream>>>(stats, gmm[2], btm[2], scl, uu);
    k_w2p<<<1024, 256, 0, stream>>>(w2[2], scl, W2p);
    k_fused<false, true><<<gF, 512, 0, stream>>>(Pb1, nullptr, srcidx, row_ptr,
                                                 w1t + (size_t)4 * 65536, Bsw3, W2p,
                                                 nullptr, kN, btt + 512, uu, batch, pooled);

    // ---------------- head ----------------
    k_head<<<kG, 64, 0, stream>>>(pooled, counts, lin_w, lin_b, out);
}

// Round 8
// 904.137 us; speedup vs baseline: 1.4996x; 1.4996x over previous
//
#include <hip/hip_runtime.h>

static const int kN = 50000;   // nodes
static const int kE = 300000;  // edges
static const int kG = 2048;    // graphs
static const int kT = 19;      // targets
static const int kSeg = kN * 4;  // CSR segments: key = dst*4 + rel
static const int kScanB = (kSeg + 256) / 256;  // 784 blocks covers kSeg+1

typedef __bf16 bf16;
typedef __bf16 bf16x8 __attribute__((ext_vector_type(8)));
typedef __bf16 bf16x4 __attribute__((ext_vector_type(4)));
typedef float  f32x4  __attribute__((ext_vector_type(4)));
typedef short  short8 __attribute__((ext_vector_type(8)));

// Non-temporal access helpers: the h1/Pb tensors are write-once/read-once
// ACROSS kernels. Cached stores leave their lines dirty in the producer
// XCD's L2 (non-coherent across XCDs) -> consumer reads pay remote-dirty
// servicing; and the 102MB h1 stream thrashes the 4MB per-XCD L2, evicting
// the reused B/Pb working set. nt stores/loads bypass L2.
__device__ __forceinline__ void nt_store_b16(bf16* p, bf16 v) {
    union { bf16 b; short s; } u; u.b = v;
    __builtin_nontemporal_store(u.s, (short*)p);
}
__device__ __forceinline__ bf16x8 nt_load8(const bf16* p) {
    short8 s = __builtin_nontemporal_load((const short8*)p);
    union { short8 s; bf16x8 b; } u; u.s = s; return u.b;
}

// ---------------------------------------------------------------------------
// GEMM1 layers 2/3: aggregate (CSR, +self) into LDS, then MFMA vs w1t[r].
// Grid (ceil(N/64), 4=rel), 512 threads (8 waves). h1 stored NON-TEMPORAL.
// ---------------------------------------------------------------------------
__global__ __launch_bounds__(512) void k_rgin1(
    const bf16* __restrict__ Pb, const int* __restrict__ srcidx,
    const int* __restrict__ row_ptr, const bf16* __restrict__ w1t,
    bf16* __restrict__ h1, float* __restrict__ stats)
{
    __shared__ bf16 As[64][264];   // row stride 264 bf16 = 132 dwords
    const int t = threadIdx.x;
    const int r = blockIdx.y;
    const int m0 = blockIdx.x * 64;
    const int wave = t >> 6, lane = t & 63;
    const int l15 = lane & 15, lq = lane >> 4, koff = lq * 8;
    const int wn = wave * 32;

    // B pointers + first-fragment prefetch (lands during phase 1)
    const bf16* Bt = w1t + (long)r * 65536;
    const bf16* Bp[2];
#pragma unroll
    for (int j = 0; j < 2; ++j)
        Bp[j] = Bt + (long)(wn + j * 16 + l15) * 256 + koff;
    bf16x8 b0[2], b1[2];
#pragma unroll
    for (int j = 0; j < 2; ++j) b0[j] = *(const bf16x8*)(Bp[j]);

    // ---- phase 1: 8 rows per wave, headers preloaded ----
    {
        const int rbase = m0 + wave * 8;
        int i0s[8], i1s[8];
#pragma unroll
        for (int rr = 0; rr < 8; ++rr) {
            int dc = rbase + rr; if (dc >= kN) dc = kN - 1;
            int seg = dc * 4 + r;
            i0s[rr] = row_ptr[seg];
            i1s[rr] = row_ptr[seg + 1];
        }
#pragma unroll
        for (int rr = 0; rr < 8; ++rr) {
            int dc = rbase + rr; if (dc >= kN) dc = kN - 1;
            bf16x4 sv = ((const bf16x4*)(Pb + (long)dc * 256))[lane];
            f32x4 a = {(float)sv[0], (float)sv[1], (float)sv[2], (float)sv[3]};
            int i = i0s[rr], i1 = i1s[rr];
            for (; i + 1 < i1; i += 2) {
                int s0 = srcidx[i], s1 = srcidx[i + 1];
                bf16x4 v0 = ((const bf16x4*)(Pb + (long)s0 * 256))[lane];
                bf16x4 v1 = ((const bf16x4*)(Pb + (long)s1 * 256))[lane];
                a[0] += (float)v0[0] + (float)v1[0];
                a[1] += (float)v0[1] + (float)v1[1];
                a[2] += (float)v0[2] + (float)v1[2];
                a[3] += (float)v0[3] + (float)v1[3];
            }
            if (i < i1) {
                bf16x4 v0 = ((const bf16x4*)(Pb + (long)srcidx[i] * 256))[lane];
                a[0] += (float)v0[0]; a[1] += (float)v0[1];
                a[2] += (float)v0[2]; a[3] += (float)v0[3];
            }
            bf16x4 o = {(bf16)a[0], (bf16)a[1], (bf16)a[2], (bf16)a[3]};
            *(bf16x4*)&As[wave * 8 + rr][lane * 4] = o;
        }
    }
    __syncthreads();

    // ---- phase 2: MFMA from LDS, B double-buffered in regs ----
    const bf16* Ar[4];
#pragma unroll
    for (int i = 0; i < 4; ++i) Ar[i] = &As[i * 16 + l15][koff];

    f32x4 acc[4][2];
#pragma unroll
    for (int i = 0; i < 4; ++i)
#pragma unroll
        for (int j = 0; j < 2; ++j) acc[i][j] = (f32x4){0.f, 0.f, 0.f, 0.f};

#pragma unroll
    for (int kt = 0; kt < 256; kt += 32) {
        int kn = kt + 32; if (kn >= 256) kn = 0;
#pragma unroll
        for (int j = 0; j < 2; ++j) b1[j] = *(const bf16x8*)(Bp[j] + kn);
        bf16x8 a[4];
#pragma unroll
        for (int i = 0; i < 4; ++i) a[i] = *(const bf16x8*)(Ar[i] + kt);
#pragma unroll
        for (int i = 0; i < 4; ++i)
#pragma unroll
            for (int j = 0; j < 2; ++j)
                acc[i][j] = __builtin_amdgcn_mfma_f32_16x16x32_bf16(a[i], b0[j], acc[i][j], 0, 0, 0);
#pragma unroll
        for (int j = 0; j < 2; ++j) b0[j] = b1[j];
    }

    // ---- epilogue: store h1 (non-temporal) + fused stats ----
    const int cB = r * 256;
    float sv[2] = {0, 0}, qv[2] = {0, 0};
#pragma unroll
    for (int i = 0; i < 4; ++i) {
        int rowb = m0 + i * 16 + lq * 4;
#pragma unroll
        for (int rr = 0; rr < 4; ++rr) {
            int gm = rowb + rr;
            if (gm < kN) {
#pragma unroll
                for (int j = 0; j < 2; ++j) {
                    int gn = wn + j * 16 + l15;
                    bf16 bv = (bf16)acc[i][j][rr];
                    nt_store_b16(&h1[(long)gm * 1024 + cB + gn], bv);
                    float f = (float)bv;
                    sv[j] += f; qv[j] += f * f;
                }
            }
        }
    }
#pragma unroll
    for (int j = 0; j < 2; ++j) {
        float s = sv[j], q = qv[j];
        s += __shfl_xor(s, 16); s += __shfl_xor(s, 32);
        q += __shfl_xor(q, 16); q += __shfl_xor(q, 32);
        if (lq == 0) {
            int gn = cB + wn + j * 16 + l15;
            atomicAdd(&stats[gn], s);
            atomicAdd(&stats[1024 + gn], q);
        }
    }
}

// ---------------------------------------------------------------------------
// GEMM1 layer 1: A = a1b[r] [N,32] bf16 (K=32, one MFMA step) + fused stats.
// h1 stored NON-TEMPORAL.
// ---------------------------------------------------------------------------
__global__ __launch_bounds__(512) void k_l1gemm(
    const bf16* __restrict__ a1b, const bf16* __restrict__ w1tL1,
    bf16* __restrict__ h1, float* __restrict__ stats)
{
    const int t = threadIdx.x;
    const int r = blockIdx.y;
    const int m0 = blockIdx.x * 128;
    const int wave = t >> 6, lane = t & 63;
    const int l15 = lane & 15, lq = lane >> 4, koff = lq * 8;
    const int wm = (wave & 1) * 64, wn = (wave >> 1) * 64;

    bf16x8 a[4], b[4];
#pragma unroll
    for (int i = 0; i < 4; ++i) {
        int gm = m0 + wm + i * 16 + l15;
        if (gm >= kN) gm = kN - 1;
        a[i] = *(const bf16x8*)(a1b + ((long)r * kN + gm) * 32 + koff);
    }
#pragma unroll
    for (int j = 0; j < 4; ++j)
        b[j] = *(const bf16x8*)(w1tL1 + (long)r * 8192 + (long)(wn + j * 16 + l15) * 32 + koff);

    f32x4 acc[4][4];
#pragma unroll
    for (int i = 0; i < 4; ++i)
#pragma unroll
        for (int j = 0; j < 4; ++j)
            acc[i][j] = __builtin_amdgcn_mfma_f32_16x16x32_bf16(a[i], b[j],
                        (f32x4){0.f, 0.f, 0.f, 0.f}, 0, 0, 0);

    const int cB = r * 256;
    float sv[4] = {0,0,0,0}, qv[4] = {0,0,0,0};
#pragma unroll
    for (int i = 0; i < 4; ++i) {
        int rowb = m0 + wm + i * 16 + lq * 4;
#pragma unroll
        for (int rr = 0; rr < 4; ++rr) {
            int gm = rowb + rr;
            if (gm < kN) {
#pragma unroll
                for (int j = 0; j < 4; ++j) {
                    int gn = wn + j * 16 + l15;
                    bf16 bv = (bf16)acc[i][j][rr];
                    nt_store_b16(&h1[(long)gm * 1024 + cB + gn], bv);
                    float f = (float)bv;
                    sv[j] += f; qv[j] += f * f;
                }
            }
        }
    }
#pragma unroll
    for (int j = 0; j < 4; ++j) {
        float s = sv[j], q = qv[j];
        s += __shfl_xor(s, 16); s += __shfl_xor(s, 32);
        q += __shfl_xor(q, 16); q += __shfl_xor(q, 32);
        if (lq == 0) {
            int gn = cB + wn + j * 16 + l15;
            atomicAdd(&stats[gn], s);
            atomicAdd(&stats[1024 + gn], q);
        }
    }
}

// ---------------------------------------------------------------------------
// GEMM2 v5nt: v5 (counted-vmcnt pipeline, 888us build) + non-temporal A
// loads (h1/Pb/xb1 are read-exactly-once here) and non-temporal C stores
// (consumed by next kernel on another XCD). B stays cached (0.65MB, re-read
// by all blocks -> L2-resident).
// ---------------------------------------------------------------------------
#define KS_PHASE(SEL, KSI, BREG, VM) do {                                     \
    bf16x8 a_[4];                                                             \
    _Pragma("unroll")                                                         \
    for (int i_ = 0; i_ < 4; ++i_)                                            \
        a_[i_] = *(const bf16x8*)&As[SEL][i_ * 16 + l15][(KSI) * 32 + koff];  \
    asm volatile("s_waitcnt vmcnt(" #VM ")" ::: "memory");                    \
    __builtin_amdgcn_sched_barrier(0);                                        \
    __builtin_amdgcn_s_setprio(1);                                            \
    _Pragma("unroll")                                                         \
    for (int i_ = 0; i_ < 4; ++i_)                                            \
        _Pragma("unroll")                                                     \
        for (int j_ = 0; j_ < 4; ++j_)                                        \
            acc[i_][j_] = __builtin_amdgcn_mfma_f32_16x16x32_bf16(            \
                a_[i_], BREG[j_], acc[i_][j_], 0, 0, 0);                      \
    __builtin_amdgcn_s_setprio(0);                                            \
    __builtin_amdgcn_sched_barrier(0);                                        \
} while (0)

template<int CHUNKS, int C1, bool PoolOut>
__global__ __launch_bounds__(256) void k_gemm2(
    const bf16* __restrict__ A1, int lda1,
    const bf16* __restrict__ A2,
    const bf16* __restrict__ Bt,
    bf16* __restrict__ Cout,
    int M, const float* __restrict__ bias,
    const float* __restrict__ scl, const float* __restrict__ shf,
    const int* __restrict__ batch, float* __restrict__ pooled)
{
    constexpr int KS = CHUNKS * 4;     // number of 32-wide k-steps
    __shared__ bf16 As[2][64][136];
    __shared__ float sclL[1024];
    __shared__ float shfL[1024];
    const int t = threadIdx.x;
    const int wave = t >> 6, lane = t & 63;
    const int l15 = lane & 15, lq = lane >> 4, koff = lq * 8;
    const int wn = wave * 64;
    const int m0 = blockIdx.x * 64;

    const int srow = t >> 4;        // staging base row 0..15 (+i*16)
    const int kg   = (t & 15) * 8;  // staging col group within chunk

    // frag-linear B bases: one 1KB contiguous load per (j, ks)
    const bf16* Bp[4];
#pragma unroll
    for (int j = 0; j < 4; ++j)
        Bp[j] = Bt + (long)(wave * 4 + j) * KS * 512 + lane * 8;

    f32x4 acc[4][4];
#pragma unroll
    for (int i = 0; i < 4; ++i)
#pragma unroll
        for (int j = 0; j < 4; ++j) acc[i][j] = (f32x4){0.f, 0.f, 0.f, 0.f};

    bf16x8 rv[4];
    auto ld_A = [&](int c) {
#pragma unroll
        for (int i = 0; i < 4; ++i) {
            int gm = m0 + srow + i * 16; if (gm >= M) gm = M - 1;
            const bf16* p = (c < C1)
                ? (A1 + (long)gm * lda1 + c * 128 + kg)
                : (A2 + (long)gm * 1024 + (c - C1) * 128 + kg);
            rv[i] = nt_load8(p);
        }
    };
    auto st_lds = [&](int c, int sel) {
        if (c >= C1) {
            int k2 = (c - C1) * 128 + kg;
            float4 s0 = *(const float4*)&sclL[k2];
            float4 s1 = *(const float4*)&sclL[k2 + 4];
            float4 t0 = *(const float4*)&shfL[k2];
            float4 t1 = *(const float4*)&shfL[k2 + 4];
            float sa[8] = {s0.x, s0.y, s0.z, s0.w, s1.x, s1.y, s1.z, s1.w};
            float ta[8] = {t0.x, t0.y, t0.z, t0.w, t1.x, t1.y, t1.z, t1.w};
#pragma unroll
            for (int i = 0; i < 4; ++i) {
                bf16x8 v = rv[i]; bf16x8 o;
#pragma unroll
                for (int u = 0; u < 8; ++u)
                    o[u] = (bf16)fmaxf(0.f, fmaf((float)v[u], sa[u], ta[u]));
                *(bf16x8*)&As[sel][srow + i * 16][kg] = o;
            }
        } else {
#pragma unroll
            for (int i = 0; i < 4; ++i)
                *(bf16x8*)&As[sel][srow + i * 16][kg] = rv[i];
        }
    };

    bf16x8 breg0[4], breg1[4];

    // ---- prologue: sf->LDS, A(0), B(0,0..1); counted waits; no full drain --
    {
        const float* src = (t < 128) ? (scl + t * 8) : (shf + (t - 128) * 8);
        float*       dst = (t < 128) ? (sclL + t * 8) : (shfL + (t - 128) * 8);
        float4 f0 = *(const float4*)src;          // 2 loads (oldest)
        float4 f1 = *(const float4*)(src + 4);
        ld_A(0);                                   // 4 loads
#pragma unroll
        for (int j = 0; j < 4; ++j) breg0[j] = *(const bf16x8*)(Bp[j]);          // 4
#pragma unroll
        for (int j = 0; j < 4; ++j) breg1[j] = *(const bf16x8*)(Bp[j] + 512);    // 4
        asm volatile("s_waitcnt vmcnt(12)" ::: "memory");  // sf done
        __builtin_amdgcn_sched_barrier(0);
        *(float4*)dst = f0; *(float4*)(dst + 4) = f1;
        asm volatile("s_waitcnt vmcnt(8)" ::: "memory");   // A(0) done
        __builtin_amdgcn_sched_barrier(0);
        st_lds(0, 0);                              // chunk 0 < C1: no BN
        asm volatile("s_waitcnt lgkmcnt(0)" ::: "memory");
        __builtin_amdgcn_s_barrier();
    }

    // ---- main loop: chunks 0 .. CHUNKS-2 (compute c, stage c+1) ----
    for (int c = 0; c < CHUNKS - 1; ++c) {
        const int sel = c & 1;
        KS_PHASE(sel, 0, breg0, 4);
#pragma unroll
        for (int j = 0; j < 4; ++j)
            breg0[j] = *(const bf16x8*)(Bp[j] + (long)(4 * c + 2) * 512);
        ld_A(c + 1);
        KS_PHASE(sel, 1, breg1, 8);
#pragma unroll
        for (int j = 0; j < 4; ++j)
            breg1[j] = *(const bf16x8*)(Bp[j] + (long)(4 * c + 3) * 512);
        KS_PHASE(sel, 2, breg0, 8);
#pragma unroll
        for (int j = 0; j < 4; ++j)
            breg0[j] = *(const bf16x8*)(Bp[j] + (long)(4 * c + 4) * 512);
        KS_PHASE(sel, 3, breg1, 4);
#pragma unroll
        for (int j = 0; j < 4; ++j)
            breg1[j] = *(const bf16x8*)(Bp[j] + (long)(4 * c + 5) * 512);
        asm volatile("s_waitcnt vmcnt(8)" ::: "memory");   // A(c+1) done
        __builtin_amdgcn_sched_barrier(0);
        st_lds(c + 1, sel ^ 1);
        asm volatile("s_waitcnt lgkmcnt(0)" ::: "memory");
        __builtin_amdgcn_s_barrier();
    }

    // ---- peeled last chunk (no staging; drain B with counted waits) ----
    {
        const int c = CHUNKS - 1, sel = c & 1;
        KS_PHASE(sel, 0, breg0, 4);
#pragma unroll
        for (int j = 0; j < 4; ++j)
            breg0[j] = *(const bf16x8*)(Bp[j] + (long)(4 * c + 2) * 512);
        KS_PHASE(sel, 1, breg1, 4);
#pragma unroll
        for (int j = 0; j < 4; ++j)
            breg1[j] = *(const bf16x8*)(Bp[j] + (long)(4 * c + 3) * 512);
        KS_PHASE(sel, 2, breg0, 4);
        KS_PHASE(sel, 3, breg1, 0);
    }

    // ---- epilogue (non-temporal C stores; pooled atomics unchanged) ----
#pragma unroll
    for (int i = 0; i < 4; ++i) {
        int rowb = m0 + i * 16 + lq * 4;
#pragma unroll
        for (int rr = 0; rr < 4; ++rr) {
            int gm = rowb + rr;
            if (gm < M) {
                int g = PoolOut ? batch[gm] : 0;
#pragma unroll
                for (int j = 0; j < 4; ++j) {
                    int gn = wn + j * 16 + l15;
                    float v = fmaxf(acc[i][j][rr] + bias[gn], 0.f);
                    if (PoolOut) atomicAdd(&pooled[(long)g * 256 + gn], v);
                    else         nt_store_b16(&Cout[(long)gm * 256 + gn], (bf16)v);
                }
            }
        }
    }
}

// ---------------------------------------------------------------------------
// CSR build
__global__ void k_hist(const int* __restrict__ ei, const int* __restrict__ et,
                       int* __restrict__ hist)
{
    int e = blockIdx.x * 256 + threadIdx.x;
    if (e >= kE) return;
    atomicAdd(&hist[ei[kE + e] * 4 + et[e]], 1);
}

__global__ void k_scan1(const int* __restrict__ hist, int* __restrict__ bsum)
{
    __shared__ int sd[256];
    int i = blockIdx.x * 256 + threadIdx.x;
    sd[threadIdx.x] = (i < kSeg) ? hist[i] : 0;
    __syncthreads();
    for (int o = 128; o > 0; o >>= 1) {
        if (threadIdx.x < o) sd[threadIdx.x] += sd[threadIdx.x + o];
        __syncthreads();
    }
    if (threadIdx.x == 0) bsum[blockIdx.x] = sd[0];
}

__global__ __launch_bounds__(1024) void k_scan2(const int* __restrict__ bsum,
                                                int* __restrict__ boff)
{
    __shared__ int sd[1024];
    int t = threadIdx.x;
    sd[t] = (t < kScanB) ? bsum[t] : 0;
    __syncthreads();
    for (int o = 1; o < 1024; o <<= 1) {
        int v = (t >= o) ? sd[t - o] : 0;
        __syncthreads();
        sd[t] += v;
        __syncthreads();
    }
    if (t < kScanB) boff[t] = (t == 0) ? 0 : sd[t - 1];
}

__global__ void k_scan3(const int* __restrict__ hist, const int* __restrict__ boff,
                        int* __restrict__ row_ptr, int* __restrict__ cursor)
{
    __shared__ int sd[256];
    int i = blockIdx.x * 256 + threadIdx.x;
    int v = (i < kSeg) ? hist[i] : 0;
    sd[threadIdx.x] = v;
    __syncthreads();
    for (int o = 1; o < 256; o <<= 1) {
        int u = (threadIdx.x >= o) ? sd[threadIdx.x - o] : 0;
        __syncthreads();
        sd[threadIdx.x] += u;
        __syncthreads();
    }
    if (i <= kSeg) {
        int excl = boff[blockIdx.x] + sd[threadIdx.x] - v;
        row_ptr[i] = excl;
        if (i < kSeg) cursor[i] = excl;
    }
}

__global__ void k_fill(const int* __restrict__ ei, const int* __restrict__ et,
                       int* __restrict__ cursor, int* __restrict__ srcidx)
{
    int e = blockIdx.x * 256 + threadIdx.x;
    if (e >= kE) return;
    int key = ei[kE + e] * 4 + et[e];
    int pos = atomicAdd(&cursor[key], 1);
    srcidx[pos] = ei[e];
}

// ---------------------------------------------------------------------------
// layer-1 aggregate: a1b[r][d][ch] = bf16( x[d][ch] + sum_src x[src][ch] ), ch<11
__global__ void k_agg11(const float* __restrict__ x, const int* __restrict__ srcidx,
                        const int* __restrict__ row_ptr, bf16* __restrict__ a1b)
{
    long gid = (long)blockIdx.x * 256 + threadIdx.x;
    if (gid >= (long)kSeg * 32) return;
    int ch  = (int)(gid & 31);
    int seg = (int)(gid >> 5);
    int d = seg >> 2, r = seg & 3;
    float acc = 0.f;
    if (ch < 11) {
        acc = x[(long)d * 11 + ch];
        int i0 = row_ptr[seg], i1 = row_ptr[seg + 1];
        for (int i = i0; i < i1; ++i) acc += x[(long)srcidx[i] * 11 + ch];
    }
    a1b[((long)r * kN + d) * 32 + ch] = (bf16)acc;
}

// x [N,11] fp32 -> xb1 [N,128] bf16 zero-padded (chunk-aligned for k_gemm2)
__global__ void k_xpad(const float* __restrict__ x, bf16* __restrict__ xb1)
{
    long gid = (long)blockIdx.x * 256 + threadIdx.x;
    if (gid >= (long)kN * 128) return;
    int c = (int)(gid & 127); long d = gid >> 7;
    xb1[gid] = (c < 11) ? (bf16)x[d * 11 + c] : (bf16)0.f;
}

// weight transpose-pack: in [K,N] fp32 -> out[n*ldout + coff + k] bf16
// (still used for w1t consumed by k_rgin1's strided reg loads)
__global__ void k_wt_s(const float* __restrict__ in, bf16* __restrict__ out,
                       int K, int N, int ldout, int coff)
{
    int i = blockIdx.x * 256 + threadIdx.x;
    if (i >= K * N) return;
    int n = i / K, k = i - n * K;
    out[(long)n * ldout + coff + k] = (bf16)in[(long)k * N + n];
}

// fragment-linear B pack for k_gemm2: in [Kin,256] fp32 (rows = source-k),
// global k = k0 + krel; element (n,k) -> out[ blk*512 + lq*128 + l15*8 + u ]
// with blk = ((n>>6)*4 + ((n>>4)&3))*KS + (k>>5).
__global__ void k_wt_f(const float* __restrict__ in, bf16* __restrict__ out,
                       int Kin, int k0, int KS)
{
    int i = blockIdx.x * 256 + threadIdx.x;
    if (i >= Kin * 256) return;
    int n = i & 255, krel = i >> 8;
    int k = k0 + krel;
    int blk = ((n >> 6) * 4 + ((n >> 4) & 3)) * KS + (k >> 5);
    int idx = blk * 512 + ((k >> 3) & 3) * 128 + (n & 15) * 8 + (k & 7);
    out[idx] = (bf16)in[(long)krel * 256 + n];
}

// layer-1 w1 pack: [4][11][256] fp32 -> [4][256][32] bf16 zero-padded
__global__ void k_wtL1(const float* __restrict__ w1, bf16* __restrict__ out)
{
    int i = blockIdx.x * 256 + threadIdx.x;
    if (i >= 4 * 256 * 32) return;
    int r = i >> 13, rem = i & 8191, n = rem >> 5, k = rem & 31;
    out[i] = (k < 11) ? (bf16)w1[(long)r * 11 * 256 + (long)k * 256 + n] : (bf16)0.f;
}

__global__ void k_bn_params(const float* __restrict__ stats,
                            const float* __restrict__ g, const float* __restrict__ bt,
                            float* __restrict__ scl, float* __restrict__ shf)
{
    int c = blockIdx.x * 256 + threadIdx.x;  // < 1024
    const float invN = 1.0f / (float)kN;
    float mu  = stats[c] * invN;
    float var = stats[1024 + c] * invN - mu * mu;
    float sc  = g[c] * rsqrtf(var + 1e-5f);
    scl[c] = sc;
    shf[c] = bt[c] - mu * sc;
}

__global__ void k_bias_total(const float* sb0, const float* b20,
                             const float* sb1, const float* b21,
                             const float* sb2, const float* b22,
                             float* __restrict__ btt)
{
    int l = blockIdx.x, j = threadIdx.x;
    const float* sb = (l == 0) ? sb0 : (l == 1) ? sb1 : sb2;
    const float* b2 = (l == 0) ? b20 : (l == 1) ? b21 : b22;
    float v = sb[j];
#pragma unroll
    for (int r = 0; r < 4; ++r) v += b2[r * 256 + j];
    btt[l * 256 + j] = v;
}

__global__ void k_counts(const int* __restrict__ batch, float* __restrict__ counts)
{
    int v = blockIdx.x * 256 + threadIdx.x;
    if (v < kN) atomicAdd(&counts[batch[v]], 1.0f);
}

__global__ __launch_bounds__(64) void k_head(const float* __restrict__ pooled,
                                             const float* __restrict__ counts,
                                             const float* __restrict__ lw,
                                             const float* __restrict__ lb,
                                             float* __restrict__ out)
{
    int g = blockIdx.x;
    int l = threadIdx.x;
    float inv = 1.0f / fmaxf(counts[g], 1.0f);
    float acc[kT];
#pragma unroll
    for (int t = 0; t < kT; ++t) acc[t] = 0.f;
    for (int k = l; k < 256; k += 64) {
        float p = pooled[((long)g << 8) + k] * inv;
#pragma unroll
        for (int t = 0; t < kT; ++t) acc[t] = fmaf(p, lw[k * kT + t], acc[t]);
    }
#pragma unroll
    for (int off = 32; off > 0; off >>= 1)
#pragma unroll
        for (int t = 0; t < kT; ++t) acc[t] += __shfl_down(acc[t], off);
    if (l == 0) {
#pragma unroll
        for (int t = 0; t < kT; ++t) out[(long)g * kT + t] = acc[t] + lb[t];
    }
}

// ---------------------------------------------------------------------------
extern "C" void kernel_launch(void* const* d_in, const int* in_sizes, int n_in,
                              void* d_out, int out_size, void* d_ws, size_t ws_size,
                              hipStream_t stream)
{
    const float* x     = (const float*)d_in[0];
    const int*   ei    = (const int*)d_in[1];
    const int*   et    = (const int*)d_in[2];
    const int*   batch = (const int*)d_in[3];

    const float *sw[3], *sb[3], *w1[3], *gmm[3], *btm[3], *w2[3], *b2[3];
    for (int l = 0; l < 3; ++l) {
        int b = 4 + l * 8;
        sw[l]  = (const float*)d_in[b + 0];
        sb[l]  = (const float*)d_in[b + 1];
        w1[l]  = (const float*)d_in[b + 2];
        // b+3 = b1 (cancels inside BatchNorm)
        gmm[l] = (const float*)d_in[b + 4];
        btm[l] = (const float*)d_in[b + 5];
        w2[l]  = (const float*)d_in[b + 6];
        b2[l]  = (const float*)d_in[b + 7];
    }
    const float* lin_w = (const float*)d_in[28];
    const float* lin_b = (const float*)d_in[29];
    float* out = (float*)d_out;
    (void)in_sizes; (void)n_in; (void)out_size;

    // ---- workspace (~186 MB) ----
    char* wsb = (char*)d_ws;
    size_t off = 0;
    auto alloc = [&](size_t bytes) { void* p = wsb + off; off = (off + bytes + 255) & ~(size_t)255; return p; };
    bf16*  Pb0    = (bf16*) alloc((size_t)kN * 256 * 2);
    bf16*  Pb1    = (bf16*) alloc((size_t)kN * 256 * 2);
    bf16*  h1     = (bf16*) alloc((size_t)kN * 1024 * 2);
    bf16*  a1b    = (bf16*) alloc((size_t)4 * kN * 32 * 2);
    bf16*  xb1    = (bf16*) alloc((size_t)kN * 128 * 2);        // padded to 128
    bf16*  w1t    = (bf16*) alloc((size_t)2 * 4 * 65536 * 2);   // layers 2,3
    bf16*  w1tL1  = (bf16*) alloc((size_t)4 * 256 * 32 * 2);
    bf16*  Bc0    = (bf16*) alloc((size_t)256 * 1152 * 2);      // frag-linear [sw_pad128 | w2]
    bf16*  Bc1    = (bf16*) alloc((size_t)256 * 1280 * 2);
    bf16*  Bc2    = (bf16*) alloc((size_t)256 * 1280 * 2);
    int*   hist   = (int*)  alloc((size_t)(kSeg + 1) * 4);
    int*   row_ptr= (int*)  alloc((size_t)(kSeg + 1) * 4);
    int*   cursor = (int*)  alloc((size_t)kSeg * 4);
    int*   srcidx = (int*)  alloc((size_t)kE * 4);
    int*   bsum   = (int*)  alloc((size_t)kScanB * 4);
    int*   boff   = (int*)  alloc((size_t)kScanB * 4);
    float* stats  = (float*)alloc(2048 * 4);
    float* scl    = (float*)alloc(1024 * 4);
    float* shf    = (float*)alloc(1024 * 4);
    float* btt    = (float*)alloc(3 * 256 * 4);
    float* pooled = (float*)alloc((size_t)kG * 256 * 4);
    float* counts = (float*)alloc(kG * 4);
    if (ws_size < off) return;  // clean absmax-fail instead of OOB crash

    const dim3 gL1((kN + 127) / 128, 4);  // l1 GEMM grid (512 thr)
    const dim3 gR((kN + 63) / 64, 4);     // rgin grid (512 thr, M-tile 64)
    const dim3 g2((kN + 63) / 64);        // GEMM2 grid (256 thr)

    // ---- CSR build (parallel scan) + weight prepack ----
    hipMemsetAsync(hist, 0, (size_t)(kSeg + 1) * 4, stream);
    k_hist<<<(kE + 255) / 256, 256, 0, stream>>>(ei, et, hist);
    k_scan1<<<kScanB, 256, 0, stream>>>(hist, bsum);
    k_scan2<<<1, 1024, 0, stream>>>(bsum, boff);
    k_scan3<<<kScanB, 256, 0, stream>>>(hist, boff, row_ptr, cursor);
    k_fill<<<(kE + 255) / 256, 256, 0, stream>>>(ei, et, cursor, srcidx);

    k_bias_total<<<3, 256, 0, stream>>>(sb[0], b2[0], sb[1], b2[1], sb[2], b2[2], btt);
    k_xpad<<<(int)(((long)kN * 128 + 255) / 256), 256, 0, stream>>>(x, xb1);
    k_wtL1<<<(4 * 256 * 32 + 255) / 256, 256, 0, stream>>>(w1[0], w1tL1);
    for (int l = 1; l < 3; ++l)
        for (int r = 0; r < 4; ++r)
            k_wt_s<<<256, 256, 0, stream>>>(w1[l] + (long)r * 65536,
                                            w1t + (long)(l - 1) * 4 * 65536 + (long)r * 65536,
                                            256, 256, 256, 0);
    // frag-linear B packs (KS = K/32): layer1 K=1152 -> KS=36, layers2/3 K=1280 -> KS=40
    hipMemsetAsync(Bc0, 0, (size_t)256 * 1152 * 2, stream);
    k_wt_f<<<(11 * 256 + 255) / 256, 256, 0, stream>>>(sw[0], Bc0, 11, 0, 36);
    k_wt_f<<<1024, 256, 0, stream>>>(w2[0], Bc0, 1024, 128, 36);
    k_wt_f<<<256, 256, 0, stream>>>(sw[1], Bc1, 256, 0, 40);
    k_wt_f<<<1024, 256, 0, stream>>>(w2[1], Bc1, 1024, 256, 40);
    k_wt_f<<<256, 256, 0, stream>>>(sw[2], Bc2, 256, 0, 40);
    k_wt_f<<<1024, 256, 0, stream>>>(w2[2], Bc2, 1024, 256, 40);

    k_counts<<<(kN + 255) / 256, 256, 0, stream>>>(batch, counts);  // counts poisoned -> must init
    hipMemsetAsync(pooled, 0, (size_t)kG * 256 * 4, stream);

    // ---------------- layer 1 ----------------
    k_agg11<<<(int)(((long)kSeg * 32 + 255) / 256), 256, 0, stream>>>(x, srcidx, row_ptr, a1b);
    hipMemsetAsync(stats, 0, 2048 * 4, stream);
    k_l1gemm<<<gL1, 512, 0, stream>>>(a1b, w1tL1, h1, stats);
    k_bn_params<<<4, 256, 0, stream>>>(stats, gmm[0], btm[0], scl, shf);
    k_gemm2<9, 1, false><<<g2, 256, 0, stream>>>(xb1, 128, h1, Bc0,
                                                 Pb0, kN, btt + 0, scl, shf, nullptr, nullptr);

    // ---------------- layer 2 ----------------
    hipMemsetAsync(stats, 0, 2048 * 4, stream);
    k_rgin1<<<gR, 512, 0, stream>>>(Pb0, srcidx, row_ptr, w1t, h1, stats);
    k_bn_params<<<4, 256, 0, stream>>>(stats, gmm[1], btm[1], scl, shf);
    k_gemm2<10, 2, false><<<g2, 256, 0, stream>>>(Pb0, 256, h1, Bc1,
                                                  Pb1, kN, btt + 256, scl, shf, nullptr, nullptr);

    // ---------------- layer 3 (pool fused into GEMM2) ----------------
    hipMemsetAsync(stats, 0, 2048 * 4, stream);
    k_rgin1<<<gR, 512, 0, stream>>>(Pb1, srcidx, row_ptr, w1t + (size_t)4 * 65536, h1, stats);
    k_bn_params<<<4, 256, 0, stream>>>(stats, gmm[2], btm[2], scl, shf);
    k_gemm2<10, 2, true><<<g2, 256, 0, stream>>>(Pb1, 256, h1, Bc2,
                                                 nullptr, kN, btt + 512, scl, shf, batch, pooled);

    // ---------------- head ----------------
    k_head<<<kG, 64, 0, stream>>>(pooled, counts, lin_w, lin_b, out);
}

// Round 10
// 886.372 us; speedup vs baseline: 1.5297x; 1.0200x over previous
//
#include <hip/hip_runtime.h>

static const int kN = 50000;   // nodes
static const int kE = 300000;  // edges
static const int kG = 2048;    // graphs
static const int kT = 19;      // targets
static const int kSeg = kN * 4;  // CSR segments: key = dst*4 + rel
static const int kScanB = (kSeg + 256) / 256;  // 784 blocks covers kSeg+1

typedef __bf16 bf16;
typedef __bf16 bf16x8 __attribute__((ext_vector_type(8)));
typedef __bf16 bf16x4 __attribute__((ext_vector_type(4)));
typedef float  f32x4  __attribute__((ext_vector_type(4)));

// ---------------------------------------------------------------------------
// GEMM1 layers 2/3: aggregate (CSR, +self) into LDS, then MFMA vs w1t[r].
// Grid (ceil(N/64), 4=rel), 512 threads (8 waves).
// ---------------------------------------------------------------------------
__global__ __launch_bounds__(512) void k_rgin1(
    const bf16* __restrict__ Pb, const int* __restrict__ srcidx,
    const int* __restrict__ row_ptr, const bf16* __restrict__ w1t,
    bf16* __restrict__ h1, float* __restrict__ stats)
{
    __shared__ bf16 As[64][264];   // row stride 264 bf16 = 132 dwords
    const int t = threadIdx.x;
    const int r = blockIdx.y;
    const int m0 = blockIdx.x * 64;
    const int wave = t >> 6, lane = t & 63;
    const int l15 = lane & 15, lq = lane >> 4, koff = lq * 8;
    const int wn = wave * 32;

    // B pointers + first-fragment prefetch (lands during phase 1)
    const bf16* Bt = w1t + (long)r * 65536;
    const bf16* Bp[2];
#pragma unroll
    for (int j = 0; j < 2; ++j)
        Bp[j] = Bt + (long)(wn + j * 16 + l15) * 256 + koff;
    bf16x8 b0[2], b1[2];
#pragma unroll
    for (int j = 0; j < 2; ++j) b0[j] = *(const bf16x8*)(Bp[j]);

    // ---- phase 1: 8 rows per wave, headers preloaded ----
    {
        const int rbase = m0 + wave * 8;
        int i0s[8], i1s[8];
#pragma unroll
        for (int rr = 0; rr < 8; ++rr) {
            int dc = rbase + rr; if (dc >= kN) dc = kN - 1;
            int seg = dc * 4 + r;
            i0s[rr] = row_ptr[seg];
            i1s[rr] = row_ptr[seg + 1];
        }
#pragma unroll
        for (int rr = 0; rr < 8; ++rr) {
            int dc = rbase + rr; if (dc >= kN) dc = kN - 1;
            bf16x4 sv = ((const bf16x4*)(Pb + (long)dc * 256))[lane];
            f32x4 a = {(float)sv[0], (float)sv[1], (float)sv[2], (float)sv[3]};
            int i = i0s[rr], i1 = i1s[rr];
            for (; i + 1 < i1; i += 2) {
                int s0 = srcidx[i], s1 = srcidx[i + 1];
                bf16x4 v0 = ((const bf16x4*)(Pb + (long)s0 * 256))[lane];
                bf16x4 v1 = ((const bf16x4*)(Pb + (long)s1 * 256))[lane];
                a[0] += (float)v0[0] + (float)v1[0];
                a[1] += (float)v0[1] + (float)v1[1];
                a[2] += (float)v0[2] + (float)v1[2];
                a[3] += (float)v0[3] + (float)v1[3];
            }
            if (i < i1) {
                bf16x4 v0 = ((const bf16x4*)(Pb + (long)srcidx[i] * 256))[lane];
                a[0] += (float)v0[0]; a[1] += (float)v0[1];
                a[2] += (float)v0[2]; a[3] += (float)v0[3];
            }
            bf16x4 o = {(bf16)a[0], (bf16)a[1], (bf16)a[2], (bf16)a[3]};
            *(bf16x4*)&As[wave * 8 + rr][lane * 4] = o;
        }
    }
    __syncthreads();

    // ---- phase 2: MFMA from LDS, B double-buffered in regs ----
    const bf16* Ar[4];
#pragma unroll
    for (int i = 0; i < 4; ++i) Ar[i] = &As[i * 16 + l15][koff];

    f32x4 acc[4][2];
#pragma unroll
    for (int i = 0; i < 4; ++i)
#pragma unroll
        for (int j = 0; j < 2; ++j) acc[i][j] = (f32x4){0.f, 0.f, 0.f, 0.f};

#pragma unroll
    for (int kt = 0; kt < 256; kt += 32) {
        int kn = kt + 32; if (kn >= 256) kn = 0;
#pragma unroll
        for (int j = 0; j < 2; ++j) b1[j] = *(const bf16x8*)(Bp[j] + kn);
        bf16x8 a[4];
#pragma unroll
        for (int i = 0; i < 4; ++i) a[i] = *(const bf16x8*)(Ar[i] + kt);
#pragma unroll
        for (int i = 0; i < 4; ++i)
#pragma unroll
            for (int j = 0; j < 2; ++j)
                acc[i][j] = __builtin_amdgcn_mfma_f32_16x16x32_bf16(a[i], b0[j], acc[i][j], 0, 0, 0);
#pragma unroll
        for (int j = 0; j < 2; ++j) b0[j] = b1[j];
    }

    // ---- epilogue: store h1 + fused stats ----
    const int cB = r * 256;
    float sv[2] = {0, 0}, qv[2] = {0, 0};
#pragma unroll
    for (int i = 0; i < 4; ++i) {
        int rowb = m0 + i * 16 + lq * 4;
#pragma unroll
        for (int rr = 0; rr < 4; ++rr) {
            int gm = rowb + rr;
            if (gm < kN) {
#pragma unroll
                for (int j = 0; j < 2; ++j) {
                    int gn = wn + j * 16 + l15;
                    bf16 bv = (bf16)acc[i][j][rr];
                    h1[(long)gm * 1024 + cB + gn] = bv;
                    float f = (float)bv;
                    sv[j] += f; qv[j] += f * f;
                }
            }
        }
    }
#pragma unroll
    for (int j = 0; j < 2; ++j) {
        float s = sv[j], q = qv[j];
        s += __shfl_xor(s, 16); s += __shfl_xor(s, 32);
        q += __shfl_xor(q, 16); q += __shfl_xor(q, 32);
        if (lq == 0) {
            int gn = cB + wn + j * 16 + l15;
            atomicAdd(&stats[gn], s);
            atomicAdd(&stats[1024 + gn], q);
        }
    }
}

// ---------------------------------------------------------------------------
// GEMM1 layer 1: A = a1b[r] [N,32] bf16 (K=32, one MFMA step) + fused stats.
// ---------------------------------------------------------------------------
__global__ __launch_bounds__(512) void k_l1gemm(
    const bf16* __restrict__ a1b, const bf16* __restrict__ w1tL1,
    bf16* __restrict__ h1, float* __restrict__ stats)
{
    const int t = threadIdx.x;
    const int r = blockIdx.y;
    const int m0 = blockIdx.x * 128;
    const int wave = t >> 6, lane = t & 63;
    const int l15 = lane & 15, lq = lane >> 4, koff = lq * 8;
    const int wm = (wave & 1) * 64, wn = (wave >> 1) * 64;

    bf16x8 a[4], b[4];
#pragma unroll
    for (int i = 0; i < 4; ++i) {
        int gm = m0 + wm + i * 16 + l15;
        if (gm >= kN) gm = kN - 1;
        a[i] = *(const bf16x8*)(a1b + ((long)r * kN + gm) * 32 + koff);
    }
#pragma unroll
    for (int j = 0; j < 4; ++j)
        b[j] = *(const bf16x8*)(w1tL1 + (long)r * 8192 + (long)(wn + j * 16 + l15) * 32 + koff);

    f32x4 acc[4][4];
#pragma unroll
    for (int i = 0; i < 4; ++i)
#pragma unroll
        for (int j = 0; j < 4; ++j)
            acc[i][j] = __builtin_amdgcn_mfma_f32_16x16x32_bf16(a[i], b[j],
                        (f32x4){0.f, 0.f, 0.f, 0.f}, 0, 0, 0);

    const int cB = r * 256;
    float sv[4] = {0,0,0,0}, qv[4] = {0,0,0,0};
#pragma unroll
    for (int i = 0; i < 4; ++i) {
        int rowb = m0 + wm + i * 16 + lq * 4;
#pragma unroll
        for (int rr = 0; rr < 4; ++rr) {
            int gm = rowb + rr;
            if (gm < kN) {
#pragma unroll
                for (int j = 0; j < 4; ++j) {
                    int gn = wn + j * 16 + l15;
                    bf16 bv = (bf16)acc[i][j][rr];
                    h1[(long)gm * 1024 + cB + gn] = bv;
                    float f = (float)bv;
                    sv[j] += f; qv[j] += f * f;
                }
            }
        }
    }
#pragma unroll
    for (int j = 0; j < 4; ++j) {
        float s = sv[j], q = qv[j];
        s += __shfl_xor(s, 16); s += __shfl_xor(s, 32);
        q += __shfl_xor(q, 16); q += __shfl_xor(q, 32);
        if (lq == 0) {
            int gn = cB + wn + j * 16 + l15;
            atomicAdd(&stats[gn], s);
            atomicAdd(&stats[1024 + gn], q);
        }
    }
}

// ---------------------------------------------------------------------------
// GEMM2 v5 (counted-vmcnt pipeline): C = relu([A1 | relu(BN(A2))] @ Bt^T + b).
//  * raw s_barrier + explicit lgkmcnt(0) instead of __syncthreads() -> the
//    per-chunk vmcnt(0) drain is gone; 8 B-loads stay in flight across the
//    barrier (steady state), A-loads for chunk c+1 issued inside ks0 phase.
//  * unconditional vector-load stream: last chunk peeled, scl/shf staged to
//    LDS once in the prologue.
//  * hand-counted s_waitcnt vmcnt(4/8) per ks phase + sched_barrier(0)
//    fences (rule #18) + setprio(1) around each 16-MFMA cluster (T5).
//  Correctness: compiler still inserts its own dependency waits, so the asm
//  vmcnt values are advisory (can only add stalls, never corrupt data).
// ---------------------------------------------------------------------------
#define KS_PHASE(SEL, KSI, BREG, VM) do {                                     \
    bf16x8 a_[4];                                                             \
    _Pragma("unroll")                                                         \
    for (int i_ = 0; i_ < 4; ++i_)                                            \
        a_[i_] = *(const bf16x8*)&As[SEL][i_ * 16 + l15][(KSI) * 32 + koff];  \
    asm volatile("s_waitcnt vmcnt(" #VM ")" ::: "memory");                    \
    __builtin_amdgcn_sched_barrier(0);                                        \
    __builtin_amdgcn_s_setprio(1);                                            \
    _Pragma("unroll")                                                         \
    for (int i_ = 0; i_ < 4; ++i_)                                            \
        _Pragma("unroll")                                                     \
        for (int j_ = 0; j_ < 4; ++j_)                                        \
            acc[i_][j_] = __builtin_amdgcn_mfma_f32_16x16x32_bf16(            \
                a_[i_], BREG[j_], acc[i_][j_], 0, 0, 0);                      \
    __builtin_amdgcn_s_setprio(0);                                            \
    __builtin_amdgcn_sched_barrier(0);                                        \
} while (0)

template<int CHUNKS, int C1, bool PoolOut>
__global__ __launch_bounds__(256) void k_gemm2(
    const bf16* __restrict__ A1, int lda1,
    const bf16* __restrict__ A2,
    const bf16* __restrict__ Bt,
    bf16* __restrict__ Cout,
    int M, const float* __restrict__ bias,
    const float* __restrict__ scl, const float* __restrict__ shf,
    const int* __restrict__ batch, float* __restrict__ pooled)
{
    constexpr int KS = CHUNKS * 4;     // number of 32-wide k-steps
    __shared__ bf16 As[2][64][136];
    __shared__ float sclL[1024];
    __shared__ float shfL[1024];
    const int t = threadIdx.x;
    const int wave = t >> 6, lane = t & 63;
    const int l15 = lane & 15, lq = lane >> 4, koff = lq * 8;
    const int wn = wave * 64;
    const int m0 = blockIdx.x * 64;

    const int srow = t >> 4;        // staging base row 0..15 (+i*16)
    const int kg   = (t & 15) * 8;  // staging col group within chunk

    // frag-linear B bases: one 1KB contiguous load per (j, ks)
    const bf16* Bp[4];
#pragma unroll
    for (int j = 0; j < 4; ++j)
        Bp[j] = Bt + (long)(wave * 4 + j) * KS * 512 + lane * 8;

    f32x4 acc[4][4];
#pragma unroll
    for (int i = 0; i < 4; ++i)
#pragma unroll
        for (int j = 0; j < 4; ++j) acc[i][j] = (f32x4){0.f, 0.f, 0.f, 0.f};

    bf16x8 rv[4];
    auto ld_A = [&](int c) {
#pragma unroll
        for (int i = 0; i < 4; ++i) {
            int gm = m0 + srow + i * 16; if (gm >= M) gm = M - 1;
            const bf16* p = (c < C1)
                ? (A1 + (long)gm * lda1 + c * 128 + kg)
                : (A2 + (long)gm * 1024 + (c - C1) * 128 + kg);
            rv[i] = *(const bf16x8*)p;
        }
    };
    auto st_lds = [&](int c, int sel) {
        if (c >= C1) {
            int k2 = (c - C1) * 128 + kg;
            float4 s0 = *(const float4*)&sclL[k2];
            float4 s1 = *(const float4*)&sclL[k2 + 4];
            float4 t0 = *(const float4*)&shfL[k2];
            float4 t1 = *(const float4*)&shfL[k2 + 4];
            float sa[8] = {s0.x, s0.y, s0.z, s0.w, s1.x, s1.y, s1.z, s1.w};
            float ta[8] = {t0.x, t0.y, t0.z, t0.w, t1.x, t1.y, t1.z, t1.w};
#pragma unroll
            for (int i = 0; i < 4; ++i) {
                bf16x8 v = rv[i]; bf16x8 o;
#pragma unroll
                for (int u = 0; u < 8; ++u)
                    o[u] = (bf16)fmaxf(0.f, fmaf((float)v[u], sa[u], ta[u]));
                *(bf16x8*)&As[sel][srow + i * 16][kg] = o;
            }
        } else {
#pragma unroll
            for (int i = 0; i < 4; ++i)
                *(bf16x8*)&As[sel][srow + i * 16][kg] = rv[i];
        }
    };

    bf16x8 breg0[4], breg1[4];

    // ---- prologue: sf->LDS, A(0), B(0,0..1); counted waits; no full drain --
    {
        const float* src = (t < 128) ? (scl + t * 8) : (shf + (t - 128) * 8);
        float*       dst = (t < 128) ? (sclL + t * 8) : (shfL + (t - 128) * 8);
        float4 f0 = *(const float4*)src;          // 2 loads (oldest)
        float4 f1 = *(const float4*)(src + 4);
        ld_A(0);                                   // 4 loads
#pragma unroll
        for (int j = 0; j < 4; ++j) breg0[j] = *(const bf16x8*)(Bp[j]);          // 4
#pragma unroll
        for (int j = 0; j < 4; ++j) breg1[j] = *(const bf16x8*)(Bp[j] + 512);    // 4
        asm volatile("s_waitcnt vmcnt(12)" ::: "memory");  // sf done
        __builtin_amdgcn_sched_barrier(0);
        *(float4*)dst = f0; *(float4*)(dst + 4) = f1;
        asm volatile("s_waitcnt vmcnt(8)" ::: "memory");   // A(0) done
        __builtin_amdgcn_sched_barrier(0);
        st_lds(0, 0);                              // chunk 0 < C1: no BN
        asm volatile("s_waitcnt lgkmcnt(0)" ::: "memory");
        __builtin_amdgcn_s_barrier();
    }

    // ---- main loop: chunks 0 .. CHUNKS-2 (compute c, stage c+1) ----
    for (int c = 0; c < CHUNKS - 1; ++c) {
        const int sel = c & 1;
        KS_PHASE(sel, 0, breg0, 4);
#pragma unroll
        for (int j = 0; j < 4; ++j)
            breg0[j] = *(const bf16x8*)(Bp[j] + (long)(4 * c + 2) * 512);
        ld_A(c + 1);
        KS_PHASE(sel, 1, breg1, 8);
#pragma unroll
        for (int j = 0; j < 4; ++j)
            breg1[j] = *(const bf16x8*)(Bp[j] + (long)(4 * c + 3) * 512);
        KS_PHASE(sel, 2, breg0, 8);
#pragma unroll
        for (int j = 0; j < 4; ++j)
            breg0[j] = *(const bf16x8*)(Bp[j] + (long)(4 * c + 4) * 512);
        KS_PHASE(sel, 3, breg1, 4);
#pragma unroll
        for (int j = 0; j < 4; ++j)
            breg1[j] = *(const bf16x8*)(Bp[j] + (long)(4 * c + 5) * 512);
        asm volatile("s_waitcnt vmcnt(8)" ::: "memory");   // A(c+1) done
        __builtin_amdgcn_sched_barrier(0);
        st_lds(c + 1, sel ^ 1);
        asm volatile("s_waitcnt lgkmcnt(0)" ::: "memory");
        __builtin_amdgcn_s_barrier();
    }

    // ---- peeled last chunk (no staging; drain B with counted waits) ----
    {
        const int c = CHUNKS - 1, sel = c & 1;
        KS_PHASE(sel, 0, breg0, 4);
#pragma unroll
        for (int j = 0; j < 4; ++j)
            breg0[j] = *(const bf16x8*)(Bp[j] + (long)(4 * c + 2) * 512);
        KS_PHASE(sel, 1, breg1, 4);
#pragma unroll
        for (int j = 0; j < 4; ++j)
            breg1[j] = *(const bf16x8*)(Bp[j] + (long)(4 * c + 3) * 512);
        KS_PHASE(sel, 2, breg0, 4);
        KS_PHASE(sel, 3, breg1, 0);
    }

    // ---- epilogue ----
#pragma unroll
    for (int i = 0; i < 4; ++i) {
        int rowb = m0 + i * 16 + lq * 4;
#pragma unroll
        for (int rr = 0; rr < 4; ++rr) {
            int gm = rowb + rr;
            if (gm < M) {
                int g = PoolOut ? batch[gm] : 0;
#pragma unroll
                for (int j = 0; j < 4; ++j) {
                    int gn = wn + j * 16 + l15;
                    float v = fmaxf(acc[i][j][rr] + bias[gn], 0.f);
                    if (PoolOut) atomicAdd(&pooled[(long)g * 256 + gn], v);
                    else         Cout[(long)gm * 256 + gn] = (bf16)v;
                }
            }
        }
    }
}

// ---------------------------------------------------------------------------
// CSR build
__global__ void k_hist(const int* __restrict__ ei, const int* __restrict__ et,
                       int* __restrict__ hist)
{
    int e = blockIdx.x * 256 + threadIdx.x;
    if (e >= kE) return;
    atomicAdd(&hist[ei[kE + e] * 4 + et[e]], 1);
}

__global__ void k_scan1(const int* __restrict__ hist, int* __restrict__ bsum)
{
    __shared__ int sd[256];
    int i = blockIdx.x * 256 + threadIdx.x;
    sd[threadIdx.x] = (i < kSeg) ? hist[i] : 0;
    __syncthreads();
    for (int o = 128; o > 0; o >>= 1) {
        if (threadIdx.x < o) sd[threadIdx.x] += sd[threadIdx.x + o];
        __syncthreads();
    }
    if (threadIdx.x == 0) bsum[blockIdx.x] = sd[0];
}

__global__ __launch_bounds__(1024) void k_scan2(const int* __restrict__ bsum,
                                                int* __restrict__ boff)
{
    __shared__ int sd[1024];
    int t = threadIdx.x;
    sd[t] = (t < kScanB) ? bsum[t] : 0;
    __syncthreads();
    for (int o = 1; o < 1024; o <<= 1) {
        int v = (t >= o) ? sd[t - o] : 0;
        __syncthreads();
        sd[t] += v;
        __syncthreads();
    }
    if (t < kScanB) boff[t] = (t == 0) ? 0 : sd[t - 1];
}

__global__ void k_scan3(const int* __restrict__ hist, const int* __restrict__ boff,
                        int* __restrict__ row_ptr, int* __restrict__ cursor)
{
    __shared__ int sd[256];
    int i = blockIdx.x * 256 + threadIdx.x;
    int v = (i < kSeg) ? hist[i] : 0;
    sd[threadIdx.x] = v;
    __syncthreads();
    for (int o = 1; o < 256; o <<= 1) {
        int u = (threadIdx.x >= o) ? sd[threadIdx.x - o] : 0;
        __syncthreads();
        sd[threadIdx.x] += u;
        __syncthreads();
    }
    if (i <= kSeg) {
        int excl = boff[blockIdx.x] + sd[threadIdx.x] - v;
        row_ptr[i] = excl;
        if (i < kSeg) cursor[i] = excl;
    }
}

__global__ void k_fill(const int* __restrict__ ei, const int* __restrict__ et,
                       int* __restrict__ cursor, int* __restrict__ srcidx)
{
    int e = blockIdx.x * 256 + threadIdx.x;
    if (e >= kE) return;
    int key = ei[kE + e] * 4 + et[e];
    int pos = atomicAdd(&cursor[key], 1);
    srcidx[pos] = ei[e];
}

// ---------------------------------------------------------------------------
// layer-1 aggregate: a1b[r][d][ch] = bf16( x[d][ch] + sum_src x[src][ch] ), ch<11
__global__ void k_agg11(const float* __restrict__ x, const int* __restrict__ srcidx,
                        const int* __restrict__ row_ptr, bf16* __restrict__ a1b)
{
    long gid = (long)blockIdx.x * 256 + threadIdx.x;
    if (gid >= (long)kSeg * 32) return;
    int ch  = (int)(gid & 31);
    int seg = (int)(gid >> 5);
    int d = seg >> 2, r = seg & 3;
    float acc = 0.f;
    if (ch < 11) {
        acc = x[(long)d * 11 + ch];
        int i0 = row_ptr[seg], i1 = row_ptr[seg + 1];
        for (int i = i0; i < i1; ++i) acc += x[(long)srcidx[i] * 11 + ch];
    }
    a1b[((long)r * kN + d) * 32 + ch] = (bf16)acc;
}

// x [N,11] fp32 -> xb1 [N,128] bf16 zero-padded (chunk-aligned for k_gemm2)
__global__ void k_xpad(const float* __restrict__ x, bf16* __restrict__ xb1)
{
    long gid = (long)blockIdx.x * 256 + threadIdx.x;
    if (gid >= (long)kN * 128) return;
    int c = (int)(gid & 127); long d = gid >> 7;
    xb1[gid] = (c < 11) ? (bf16)x[d * 11 + c] : (bf16)0.f;
}

// weight transpose-pack: in [K,N] fp32 -> out[n*ldout + coff + k] bf16
// (still used for w1t consumed by k_rgin1's strided reg loads)
__global__ void k_wt_s(const float* __restrict__ in, bf16* __restrict__ out,
                       int K, int N, int ldout, int coff)
{
    int i = blockIdx.x * 256 + threadIdx.x;
    if (i >= K * N) return;
    int n = i / K, k = i - n * K;
    out[(long)n * ldout + coff + k] = (bf16)in[(long)k * N + n];
}

// fragment-linear B pack for k_gemm2: in [Kin,256] fp32 (rows = source-k),
// global k = k0 + krel; element (n,k) -> out[ blk*512 + lq*128 + l15*8 + u ]
// with blk = ((n>>6)*4 + ((n>>4)&3))*KS + (k>>5), lq=(k>>3)&3, l15=n&15, u=k&7.
// Matches k_gemm2's read: Bp[j] + kn*512, Bp[j] = Bt + (w*4+j)*KS*512 + lane*8.
__global__ void k_wt_f(const float* __restrict__ in, bf16* __restrict__ out,
                       int Kin, int k0, int KS)
{
    int i = blockIdx.x * 256 + threadIdx.x;
    if (i >= Kin * 256) return;
    int n = i & 255, krel = i >> 8;
    int k = k0 + krel;
    int blk = ((n >> 6) * 4 + ((n >> 4) & 3)) * KS + (k >> 5);
    int idx = blk * 512 + ((k >> 3) & 3) * 128 + (n & 15) * 8 + (k & 7);
    out[idx] = (bf16)in[(long)krel * 256 + n];
}

// layer-1 w1 pack: [4][11][256] fp32 -> [4][256][32] bf16 zero-padded
__global__ void k_wtL1(const float* __restrict__ w1, bf16* __restrict__ out)
{
    int i = blockIdx.x * 256 + threadIdx.x;
    if (i >= 4 * 256 * 32) return;
    int r = i >> 13, rem = i & 8191, n = rem >> 5, k = rem & 31;
    out[i] = (k < 11) ? (bf16)w1[(long)r * 11 * 256 + (long)k * 256 + n] : (bf16)0.f;
}

__global__ void k_bn_params(const float* __restrict__ stats,
                            const float* __restrict__ g, const float* __restrict__ bt,
                            float* __restrict__ scl, float* __restrict__ shf)
{
    int c = blockIdx.x * 256 + threadIdx.x;  // < 1024
    const float invN = 1.0f / (float)kN;
    float mu  = stats[c] * invN;
    float var = stats[1024 + c] * invN - mu * mu;
    float sc  = g[c] * rsqrtf(var + 1e-5f);
    scl[c] = sc;
    shf[c] = bt[c] - mu * sc;
}

__global__ void k_bias_total(const float* sb0, const float* b20,
                             const float* sb1, const float* b21,
                             const float* sb2, const float* b22,
                             float* __restrict__ btt)
{
    int l = blockIdx.x, j = threadIdx.x;
    const float* sb = (l == 0) ? sb0 : (l == 1) ? sb1 : sb2;
    const float* b2 = (l == 0) ? b20 : (l == 1) ? b21 : b22;
    float v = sb[j];
#pragma unroll
    for (int r = 0; r < 4; ++r) v += b2[r * 256 + j];
    btt[l * 256 + j] = v;
}

__global__ void k_counts(const int* __restrict__ batch, float* __restrict__ counts)
{
    int v = blockIdx.x * 256 + threadIdx.x;
    if (v < kN) atomicAdd(&counts[batch[v]], 1.0f);
}

__global__ __launch_bounds__(64) void k_head(const float* __restrict__ pooled,
                                             const float* __restrict__ counts,
                                             const float* __restrict__ lw,
                                             const float* __restrict__ lb,
                                             float* __restrict__ out)
{
    int g = blockIdx.x;
    int l = threadIdx.x;
    float inv = 1.0f / fmaxf(counts[g], 1.0f);
    float acc[kT];
#pragma unroll
    for (int t = 0; t < kT; ++t) acc[t] = 0.f;
    for (int k = l; k < 256; k += 64) {
        float p = pooled[((long)g << 8) + k] * inv;
#pragma unroll
        for (int t = 0; t < kT; ++t) acc[t] = fmaf(p, lw[k * kT + t], acc[t]);
    }
#pragma unroll
    for (int off = 32; off > 0; off >>= 1)
#pragma unroll
        for (int t = 0; t < kT; ++t) acc[t] += __shfl_down(acc[t], off);
    if (l == 0) {
#pragma unroll
        for (int t = 0; t < kT; ++t) out[(long)g * kT + t] = acc[t] + lb[t];
    }
}

// ---------------------------------------------------------------------------
extern "C" void kernel_launch(void* const* d_in, const int* in_sizes, int n_in,
                              void* d_out, int out_size, void* d_ws, size_t ws_size,
                              hipStream_t stream)
{
    const float* x     = (const float*)d_in[0];
    const int*   ei    = (const int*)d_in[1];
    const int*   et    = (const int*)d_in[2];
    const int*   batch = (const int*)d_in[3];

    const float *sw[3], *sb[3], *w1[3], *gmm[3], *btm[3], *w2[3], *b2[3];
    for (int l = 0; l < 3; ++l) {
        int b = 4 + l * 8;
        sw[l]  = (const float*)d_in[b + 0];
        sb[l]  = (const float*)d_in[b + 1];
        w1[l]  = (const float*)d_in[b + 2];
        // b+3 = b1 (cancels inside BatchNorm)
        gmm[l] = (const float*)d_in[b + 4];
        btm[l] = (const float*)d_in[b + 5];
        w2[l]  = (const float*)d_in[b + 6];
        b2[l]  = (const float*)d_in[b + 7];
    }
    const float* lin_w = (const float*)d_in[28];
    const float* lin_b = (const float*)d_in[29];
    float* out = (float*)d_out;
    (void)in_sizes; (void)n_in; (void)out_size;

    // ---- workspace (~186 MB) ----
    char* wsb = (char*)d_ws;
    size_t off = 0;
    auto alloc = [&](size_t bytes) { void* p = wsb + off; off = (off + bytes + 255) & ~(size_t)255; return p; };
    bf16*  Pb0    = (bf16*) alloc((size_t)kN * 256 * 2);
    bf16*  Pb1    = (bf16*) alloc((size_t)kN * 256 * 2);
    bf16*  h1     = (bf16*) alloc((size_t)kN * 1024 * 2);
    bf16*  a1b    = (bf16*) alloc((size_t)4 * kN * 32 * 2);
    bf16*  xb1    = (bf16*) alloc((size_t)kN * 128 * 2);        // padded to 128
    bf16*  w1t    = (bf16*) alloc((size_t)2 * 4 * 65536 * 2);   // layers 2,3
    bf16*  w1tL1  = (bf16*) alloc((size_t)4 * 256 * 32 * 2);
    bf16*  Bc0    = (bf16*) alloc((size_t)256 * 1152 * 2);      // frag-linear [sw_pad128 | w2]
    bf16*  Bc1    = (bf16*) alloc((size_t)256 * 1280 * 2);
    bf16*  Bc2    = (bf16*) alloc((size_t)256 * 1280 * 2);
    int*   hist   = (int*)  alloc((size_t)(kSeg + 1) * 4);
    int*   row_ptr= (int*)  alloc((size_t)(kSeg + 1) * 4);
    int*   cursor = (int*)  alloc((size_t)kSeg * 4);
    int*   srcidx = (int*)  alloc((size_t)kE * 4);
    int*   bsum   = (int*)  alloc((size_t)kScanB * 4);
    int*   boff   = (int*)  alloc((size_t)kScanB * 4);
    float* stats  = (float*)alloc(2048 * 4);
    float* scl    = (float*)alloc(1024 * 4);
    float* shf    = (float*)alloc(1024 * 4);
    float* btt    = (float*)alloc(3 * 256 * 4);
    float* pooled = (float*)alloc((size_t)kG * 256 * 4);
    float* counts = (float*)alloc(kG * 4);
    if (ws_size < off) return;  // clean absmax-fail instead of OOB crash

    const dim3 gL1((kN + 127) / 128, 4);  // l1 GEMM grid (512 thr)
    const dim3 gR((kN + 63) / 64, 4);     // rgin grid (512 thr, M-tile 64)
    const dim3 g2((kN + 63) / 64);        // GEMM2 grid (256 thr)

    // ---- CSR build (parallel scan) + weight prepack ----
    hipMemsetAsync(hist, 0, (size_t)(kSeg + 1) * 4, stream);
    k_hist<<<(kE + 255) / 256, 256, 0, stream>>>(ei, et, hist);
    k_scan1<<<kScanB, 256, 0, stream>>>(hist, bsum);
    k_scan2<<<1, 1024, 0, stream>>>(bsum, boff);
    k_scan3<<<kScanB, 256, 0, stream>>>(hist, boff, row_ptr, cursor);
    k_fill<<<(kE + 255) / 256, 256, 0, stream>>>(ei, et, cursor, srcidx);

    k_bias_total<<<3, 256, 0, stream>>>(sb[0], b2[0], sb[1], b2[1], sb[2], b2[2], btt);
    k_xpad<<<(int)(((long)kN * 128 + 255) / 256), 256, 0, stream>>>(x, xb1);
    k_wtL1<<<(4 * 256 * 32 + 255) / 256, 256, 0, stream>>>(w1[0], w1tL1);
    for (int l = 1; l < 3; ++l)
        for (int r = 0; r < 4; ++r)
            k_wt_s<<<256, 256, 0, stream>>>(w1[l] + (long)r * 65536,
                                            w1t + (long)(l - 1) * 4 * 65536 + (long)r * 65536,
                                            256, 256, 256, 0);
    // frag-linear B packs (KS = K/32): layer1 K=1152 -> KS=36, layers2/3 K=1280 -> KS=40
    hipMemsetAsync(Bc0, 0, (size_t)256 * 1152 * 2, stream);
    k_wt_f<<<(11 * 256 + 255) / 256, 256, 0, stream>>>(sw[0], Bc0, 11, 0, 36);
    k_wt_f<<<1024, 256, 0, stream>>>(w2[0], Bc0, 1024, 128, 36);
    k_wt_f<<<256, 256, 0, stream>>>(sw[1], Bc1, 256, 0, 40);
    k_wt_f<<<1024, 256, 0, stream>>>(w2[1], Bc1, 1024, 256, 40);
    k_wt_f<<<256, 256, 0, stream>>>(sw[2], Bc2, 256, 0, 40);
    k_wt_f<<<1024, 256, 0, stream>>>(w2[2], Bc2, 1024, 256, 40);

    k_counts<<<(kN + 255) / 256, 256, 0, stream>>>(batch, counts);  // counts poisoned -> must init
    hipMemsetAsync(pooled, 0, (size_t)kG * 256 * 4, stream);

    // ---------------- layer 1 ----------------
    k_agg11<<<(int)(((long)kSeg * 32 + 255) / 256), 256, 0, stream>>>(x, srcidx, row_ptr, a1b);
    hipMemsetAsync(stats, 0, 2048 * 4, stream);
    k_l1gemm<<<gL1, 512, 0, stream>>>(a1b, w1tL1, h1, stats);
    k_bn_params<<<4, 256, 0, stream>>>(stats, gmm[0], btm[0], scl, shf);
    k_gemm2<9, 1, false><<<g2, 256, 0, stream>>>(xb1, 128, h1, Bc0,
                                                 Pb0, kN, btt + 0, scl, shf, nullptr, nullptr);

    // ---------------- layer 2 ----------------
    hipMemsetAsync(stats, 0, 2048 * 4, stream);
    k_rgin1<<<gR, 512, 0, stream>>>(Pb0, srcidx, row_ptr, w1t, h1, stats);
    k_bn_params<<<4, 256, 0, stream>>>(stats, gmm[1], btm[1], scl, shf);
    k_gemm2<10, 2, false><<<g2, 256, 0, stream>>>(Pb0, 256, h1, Bc1,
                                                  Pb1, kN, btt + 256, scl, shf, nullptr, nullptr);

    // ---------------- layer 3 (pool fused into GEMM2) ----------------
    hipMemsetAsync(stats, 0, 2048 * 4, stream);
    k_rgin1<<<gR, 512, 0, stream>>>(Pb1, srcidx, row_ptr, w1t + (size_t)4 * 65536, h1, stats);
    k_bn_params<<<4, 256, 0, stream>>>(stats, gmm[2], btm[2], scl, shf);
    k_gemm2<10, 2, true><<<g2, 256, 0, stream>>>(Pb1, 256, h1, Bc2,
                                                 nullptr, kN, btt + 512, scl, shf, batch, pooled);

    // ---------------- head ----------------
    k_head<<<kG, 64, 0, stream>>>(pooled, counts, lin_w, lin_b, out);
}